// Round 8
// baseline (8683.980 us; speedup 1.0000x reference)
//
#include <hip/hip_runtime.h>

typedef unsigned short ushort_t;
typedef unsigned int uint_t;
typedef __bf16 bf16x8 __attribute__((ext_vector_type(8)));
typedef float f32x4 __attribute__((ext_vector_type(4)));

#define T_STEPS 512
#define NWG 256
#define GL_P 33  // gate-tile stride in f32

__device__ __forceinline__ float bf2f(ushort_t u) {
  union { unsigned u; float f; } v; v.u = ((unsigned)u) << 16; return v.f;
}
__device__ __forceinline__ ushort_t f2bf(float f) {
  union { float f; unsigned u; } v; v.f = f;
  unsigned r = (v.u + 0x7FFFu + ((v.u >> 16) & 1u)) >> 16;
  return (ushort_t)r;
}
__device__ __forceinline__ uint_t pack2(float a, float b) {
  return (uint_t)f2bf(a) | ((uint_t)f2bf(b) << 16);
}
__device__ __forceinline__ float sigf(float x) {
  return 1.0f / (1.0f + __expf(-x));
}
union bfu { uint4 u; bf16x8 v; };

// ---------------------------------------------------------------------------
// fp32 -> bf16, vectorized, grid-stride
// ---------------------------------------------------------------------------
__global__ void __launch_bounds__(256) cvt_f32_bf16(
    const float* __restrict__ in, ushort_t* __restrict__ outp, int n4) {
  int i = blockIdx.x * 256 + threadIdx.x;
  const int stride = gridDim.x * 256;
  for (; i < n4; i += stride) {
    float4 v = ((const float4*)in)[i];
    ushort4 o;
    o.x = f2bf(v.x); o.y = f2bf(v.y); o.z = f2bf(v.z); o.w = f2bf(v.w);
    ((ushort4*)outp)[i] = o;
  }
}

// ---------------------------------------------------------------------------
// W1 -> per-WG permuted bf16: Wp1 row pr = [wgl=pr>>5][c=pr&31],
// src row = (c>>3)*1024 + wgl*8 + (c&7). One block per row, 256 thr x float4.
// ---------------------------------------------------------------------------
__global__ void __launch_bounds__(256) cvt_permW1(
    const float* __restrict__ W1, ushort_t* __restrict__ Wp1) {
  int pr = blockIdx.x;
  int wgl = pr >> 5, c = pr & 31;
  int srcr = ((c >> 3) << 10) + (wgl << 3) + (c & 7);
  const float4* s = (const float4*)(W1 + (size_t)srcr * 1024);
  ushort4* d = (ushort4*)(Wp1 + (size_t)pr * 1024);
  float4 v = s[threadIdx.x];
  ushort4 o;
  o.x = f2bf(v.x); o.y = f2bf(v.y); o.z = f2bf(v.z); o.w = f2bf(v.w);
  d[threadIdx.x] = o;
}

// ---------------------------------------------------------------------------
// GEMM: xg0p[m][pc] = sum_k X[m][k]*W0[n][k] + bi0[n], column-permuted
// pc = ((n&1023)>>3)*32 + (n&7)*4 + (n>>10).  X fp32 (reg-staged cvt), W bf16.
// ---------------------------------------------------------------------------
__global__ void __launch_bounds__(256, 1) gemm_xg(
    const float* __restrict__ X, const ushort_t* __restrict__ Wm,
    const float* __restrict__ bi, ushort_t* __restrict__ outp) {
  __shared__ char smem[65536];
  const int tid = threadIdx.x;
  const int lane = tid & 63, w = tid >> 6;
  const int m0 = blockIdx.x * 128, n0 = blockIdx.y * 128;
  const int wr = w >> 1, wc = w & 1;
  const int lr = lane & 15, kg = lane >> 4;
  const int ar_ = tid & 127;
  const int abq = (tid >> 7) * 4;

  f32x4 acc[4][4] = {};
  float4 fa[8];

  auto stageA_issue = [&](int kt) {
    const float* src = X + (size_t)(m0 + ar_) * 1024 + kt * 64 + abq * 8;
#pragma unroll
    for (int i = 0; i < 4; ++i) {
      fa[2 * i] = *(const float4*)(src + i * 8);
      fa[2 * i + 1] = *(const float4*)(src + i * 8 + 4);
    }
  };
  auto stageA_write = [&](int p) {
    char* sA = smem + p * 32768;
#pragma unroll
    for (int i = 0; i < 4; ++i) {
      int blk = abq + i;
      uint4 o;
      o.x = pack2(fa[2 * i].x, fa[2 * i].y);
      o.y = pack2(fa[2 * i].z, fa[2 * i].w);
      o.z = pack2(fa[2 * i + 1].x, fa[2 * i + 1].y);
      o.w = pack2(fa[2 * i + 1].z, fa[2 * i + 1].w);
      *(uint4*)(sA + ar_ * 128 + ((blk ^ (ar_ & 7)) << 4)) = o;
    }
  };
  auto stageB = [&](int kt, int p) {
    const int ks = kt * 64;
    char* sB = smem + p * 32768 + 16384;
#pragma unroll
    for (int i = 0; i < 4; ++i) {
      int wi = w * 4 + i;
      int e = wi * 64 + lane;
      int row = e >> 3, pb = e & 7;
      int kb = pb ^ (row & 7);
      const ushort_t* gB = Wm + (size_t)(n0 + row) * 1024 + ks + kb * 8;
      __builtin_amdgcn_global_load_lds(
          (const __attribute__((address_space(1))) void*)gB,
          (__attribute__((address_space(3))) void*)(sB + wi * 1024), 16, 0, 0);
    }
  };

  stageA_issue(0);
  stageB(0, 0);
  stageA_write(0);
  __syncthreads();
#pragma unroll 1
  for (int kt = 0; kt < 16; ++kt) {
    const int p = kt & 1;
    if (kt < 15) { stageA_issue(kt + 1); stageB(kt + 1, p ^ 1); }
    const char* sA = smem + p * 32768;
    const char* sB = sA + 16384;
#pragma unroll
    for (int k2 = 0; k2 < 2; ++k2) {
      bf16x8 af[4], bf[4];
#pragma unroll
      for (int mt = 0; mt < 4; ++mt) {
        int ar = wr * 64 + mt * 16 + lr;
        int kb = k2 * 4 + kg;
        af[mt] = *(const bf16x8*)(sA + ar * 128 + ((kb ^ (ar & 7)) << 4));
      }
#pragma unroll
      for (int nt = 0; nt < 4; ++nt) {
        int br = wc * 64 + nt * 16 + lr;
        int kb = k2 * 4 + kg;
        bf[nt] = *(const bf16x8*)(sB + br * 128 + ((kb ^ (br & 7)) << 4));
      }
#pragma unroll
      for (int mt = 0; mt < 4; ++mt)
#pragma unroll
        for (int nt = 0; nt < 4; ++nt)
          acc[mt][nt] = __builtin_amdgcn_mfma_f32_16x16x32_bf16(
              af[mt], bf[nt], acc[mt][nt], 0, 0, 0);
    }
    if (kt < 15) stageA_write(p ^ 1);
    __syncthreads();
  }
#pragma unroll
  for (int nt = 0; nt < 4; ++nt) {
    int gc = n0 + wc * 64 + nt * 16 + lr;
    int pc = ((gc & 1023) >> 3) * 32 + (gc & 7) * 4 + (gc >> 10);
    float bv = bi[gc];
#pragma unroll
    for (int mt = 0; mt < 4; ++mt) {
#pragma unroll
      for (int r = 0; r < 4; ++r) {
        int gr = m0 + wr * 64 + mt * 16 + kg * 4 + r;
        outp[(size_t)gr * 4096 + pc] = f2bf(acc[mt][nt][r] + bv);
      }
    }
  }
}

// ---------------------------------------------------------------------------
// Fused 2-layer wavefront recurrence. 256 WGs x 256 thr (1 WG/CU).
// R fragments live in 128 VGPRs per lane (loaded once). hl XOR-swizzled.
// Layer-1: single K=2048 pass, [h1(t-1); h0(t)] @ [R1; W1]^T; W1 streamed
// from per-WG-permuted Wp1 (L2-resident). h exchange via sc0/sc1 L3 ops.
// gates i,o,z,f:  c = c*f + z - i;  h = sig(c) - o.
// ---------------------------------------------------------------------------
__global__ void __launch_bounds__(256, 1) fused_rec(
    const ushort_t* __restrict__ xg0p, const float* __restrict__ R0,
    const float* __restrict__ R1, const ushort_t* __restrict__ Wp1,
    const float* __restrict__ bh0, const float* __restrict__ bi1,
    const float* __restrict__ bh1, const float* __restrict__ h0_all,
    const float* __restrict__ c0_all, float* __restrict__ out_f,
    float* __restrict__ hfinb, float* __restrict__ cfinb,
    ushort_t* __restrict__ hpp0, ushort_t* __restrict__ hpp1,
    uint_t* __restrict__ flags) {
  extern __shared__ char smem[];
  char* hl = smem;                     // [64 rows][2048 B] XOR-swizzled bf16
  float* gl = (float*)(smem + 131072); // [32][GL_P] f32

  const int tid = threadIdx.x;
  const int wg = blockIdx.x;
  const int layer = wg >> 7;
  const int wgl = wg & 127;
  const int j0 = wgl * 8;
  const int lane = tid & 63, w = tid >> 6;
  const int mt16 = (w >> 1) << 4, nt16 = (w & 1) << 4;
  const int lr = lane & 15, kg = lane >> 4;
  const int b = tid >> 3, jj = tid & 7;
  const int arow_i = mt16 + lr;        // A row (batch) this lane reads
  const int rx = arow_i & 7;           // swizzle key (same for row+32)

  // --- one-time: R slice fragments -> registers (B is time-invariant) ---
  const int bcol = nt16 + lr;  // 0..31: gate bcol>>3, hid j0+(bcol&7)
  bf16x8 breg[32];
  {
    const int brow = ((bcol >> 3) << 10) + j0 + (bcol & 7);
    const float* rsrc = (layer ? R1 : R0) + (size_t)brow * 1024 + kg * 8;
#pragma unroll
    for (int kt = 0; kt < 32; ++kt) {
      float4 f0 = *(const float4*)(rsrc + kt * 32);
      float4 f1 = *(const float4*)(rsrc + kt * 32 + 4);
      bfu o;
      o.u.x = pack2(f0.x, f0.y); o.u.y = pack2(f0.z, f0.w);
      o.u.z = pack2(f1.x, f1.y); o.u.w = pack2(f1.z, f1.w);
      breg[kt] = o.v;
    }
  }
  const ushort_t* wrow = Wp1 + ((size_t)(wgl * 32 + bcol)) * 1024 + kg * 8;

  float bhv[4];
#pragma unroll
  for (int g = 0; g < 4; ++g) {
    int gi = g * 1024 + j0 + jj;
    bhv[g] = layer ? (bi1[gi] + bh1[gi]) : bh0[gi];
  }
  const int cidx = b * 1024 + j0 + jj;
  float c_st = c0_all[layer * 32768 + cidx];
  float* hfin = hfinb + layer * 32768;
  float* cfin = cfinb + layer * 32768;
  uint_t* hppd = (uint_t*)(layer ? hpp1 : hpp0);

  // swizzled LDS stage: logical (row, 16B-block kb) -> hl
  auto ldsw = [&](int row, int kb, uint4 v) {
    *(uint4*)(hl + row * 2048 + ((kb ^ (row & 7)) << 4)) = v;
  };
  // cvt-stage 32 rows from fp32 src into rows [rbase, rbase+32)
  auto cvt_stage = [&](const float* src32, int rbase) {
#pragma unroll 2
    for (int it = 0; it < 16; ++it) {
      int idx = it * 256 + tid;
      int r = idx >> 7, kb = idx & 127;
      const float* src = src32 + (size_t)r * 1024 + kb * 8;
      float4 f0 = *(const float4*)src;
      float4 f1 = *(const float4*)(src + 4);
      uint4 o;
      o.x = pack2(f0.x, f0.y); o.y = pack2(f0.z, f0.w);
      o.z = pack2(f1.x, f1.y); o.w = pack2(f1.z, f1.w);
      ldsw(rbase + r, kb, o);
    }
  };

  for (int s = 0; s <= T_STEPS; ++s) {
    const bool active = layer ? (s >= 1) : (s < T_STEPS);
    if (active) {
      const int t = layer ? (s - 1) : s;
      float hv;
      f32x4 acc = {0.f, 0.f, 0.f, 0.f};
      if (layer == 0) {
        uint2 xgu = *(const uint2*)(xg0p + (size_t)(t * 32 + b) * 4096 +
                                    wgl * 32 + jj * 4);
        if (t == 0) {
          cvt_stage(h0_all, 0);
        } else {
          uint4 hv4[16];
          const char* hsrc = (const char*)hpp0 + (((t - 1) & 1) << 16);
#pragma unroll
          for (int it = 0; it < 16; ++it)
            asm volatile("global_load_dwordx4 %0, %1, off sc0 sc1"
                         : "=v"(hv4[it])
                         : "v"(hsrc + (it * 256 + tid) * 16));
          asm volatile("s_waitcnt vmcnt(0)" ::: "memory");
#pragma unroll
          for (int it = 0; it < 16; ++it) {
            int idx = it * 256 + tid;
            ldsw(idx >> 7, idx & 127, hv4[it]);
          }
        }
        __syncthreads();
        const char* arow = hl + arow_i * 2048;
#pragma unroll 8
        for (int kt = 0; kt < 32; ++kt) {
          int kb = kt * 4 + kg;
          bf16x8 a = *(const bf16x8*)(arow + ((kb ^ rx) << 4));
          acc = __builtin_amdgcn_mfma_f32_16x16x32_bf16(a, breg[kt], acc,
                                                        0, 0, 0);
        }
#pragma unroll
        for (int r = 0; r < 4; ++r)
          gl[(mt16 + kg * 4 + r) * GL_P + nt16 + lr] = acc[r];
        __syncthreads();
        float pre0 = gl[b * GL_P + 0 + jj] + bf2f((ushort_t)(xgu.x & 0xffff)) + bhv[0];
        float pre1 = gl[b * GL_P + 8 + jj] + bf2f((ushort_t)(xgu.x >> 16)) + bhv[1];
        float pre2 = gl[b * GL_P + 16 + jj] + bf2f((ushort_t)(xgu.y & 0xffff)) + bhv[2];
        float pre3 = gl[b * GL_P + 24 + jj] + bf2f((ushort_t)(xgu.y >> 16)) + bhv[3];
        float ig = sigf(pre0), og = sigf(pre1), zg = sigf(pre2), fg = sigf(pre3);
        c_st = c_st * fg + zg - ig;
        hv = sigf(c_st) - og;
      } else {
        // ---- layer 1: one staged pass, K=2048 ----
        const char* h0src = (const char*)hpp0 + ((t & 1) << 16);
        if (t == 0) {
          uint4 h0v4[16];
#pragma unroll
          for (int it = 0; it < 16; ++it)
            asm volatile("global_load_dwordx4 %0, %1, off sc0 sc1"
                         : "=v"(h0v4[it])
                         : "v"(h0src + (it * 256 + tid) * 16));
          cvt_stage(h0_all + 32768, 0);  // h1(-1) rows 0..31
          asm volatile("s_waitcnt vmcnt(0)" ::: "memory");
#pragma unroll
          for (int it = 0; it < 16; ++it) {
            int idx = it * 256 + tid;
            ldsw(32 + (idx >> 7), idx & 127, h0v4[it]);
          }
        } else {
          uint4 hv4[32];
          const char* h1src = (const char*)hpp1 + (((t - 1) & 1) << 16);
#pragma unroll
          for (int it = 0; it < 16; ++it)
            asm volatile("global_load_dwordx4 %0, %1, off sc0 sc1"
                         : "=v"(hv4[it])
                         : "v"(h1src + (it * 256 + tid) * 16));
#pragma unroll
          for (int it = 0; it < 16; ++it)
            asm volatile("global_load_dwordx4 %0, %1, off sc0 sc1"
                         : "=v"(hv4[16 + it])
                         : "v"(h0src + (it * 256 + tid) * 16));
          asm volatile("s_waitcnt vmcnt(0)" ::: "memory");
#pragma unroll
          for (int it = 0; it < 16; ++it) {
            int idx = it * 256 + tid;
            ldsw(idx >> 7, idx & 127, hv4[it]);
            ldsw(32 + (idx >> 7), idx & 127, hv4[16 + it]);
          }
        }
        __syncthreads();
        const char* arow = hl + arow_i * 2048;
        const char* arow2 = arow + 65536;  // +32 rows
#pragma unroll 8
        for (int kt = 0; kt < 32; ++kt) {
          int kb = kt * 4 + kg;
          bf16x8 a = *(const bf16x8*)(arow + ((kb ^ rx) << 4));
          acc = __builtin_amdgcn_mfma_f32_16x16x32_bf16(a, breg[kt], acc,
                                                        0, 0, 0);
        }
#pragma unroll 8
        for (int kt = 0; kt < 32; ++kt) {
          int kb = kt * 4 + kg;
          bf16x8 a = *(const bf16x8*)(arow2 + ((kb ^ rx) << 4));
          bf16x8 bb = *(const bf16x8*)(wrow + kt * 32);
          acc = __builtin_amdgcn_mfma_f32_16x16x32_bf16(a, bb, acc, 0, 0, 0);
        }
#pragma unroll
        for (int r = 0; r < 4; ++r)
          gl[(mt16 + kg * 4 + r) * GL_P + nt16 + lr] = acc[r];
        __syncthreads();
        float pre0 = gl[b * GL_P + 0 + jj] + bhv[0];
        float pre1 = gl[b * GL_P + 8 + jj] + bhv[1];
        float pre2 = gl[b * GL_P + 16 + jj] + bhv[2];
        float pre3 = gl[b * GL_P + 24 + jj] + bhv[3];
        float ig = sigf(pre0), og = sigf(pre1), zg = sigf(pre2), fg = sigf(pre3);
        c_st = c_st * fg + zg - ig;
        hv = sigf(c_st) - og;
        out_f[(size_t)t * 32768 + cidx] = hv;
      }
      // publish h(t): packed bf16 pair, L3-coherent
      ushort_t hb = f2bf(hv);
      int partner = __shfl_down((int)hb, 1, 64);
      if ((tid & 1) == 0) {
        uint_t packed = (uint_t)hb | (((uint_t)(unsigned short)partner) << 16);
        uint_t* dst = hppd + (((t & 1) << 14) + (cidx >> 1));
        asm volatile("global_store_dword %0, %1, off sc0 sc1"
                     :: "v"(dst), "v"(packed) : "memory");
      }
      if (t == T_STEPS - 1) {
        hfin[cidx] = hv;
        cfin[cidx] = c_st;
      }
    }
    if (s < T_STEPS) {
      const uint_t gen1 = (uint_t)s + 1u;
      asm volatile("s_waitcnt vmcnt(0)" ::: "memory");
      __syncthreads();
      if (tid == 0)
        __hip_atomic_store(&flags[wg], gen1, __ATOMIC_RELAXED,
                           __HIP_MEMORY_SCOPE_AGENT);
      while (__hip_atomic_load(&flags[tid], __ATOMIC_RELAXED,
                               __HIP_MEMORY_SCOPE_AGENT) < gen1) {
        __builtin_amdgcn_s_sleep(1);
      }
      __syncthreads();
      asm volatile("" ::: "memory");
    }
  }
}

// ---------------------------------------------------------------------------
extern "C" void kernel_launch(void* const* d_in, const int* in_sizes, int n_in,
                              void* d_out, int out_size, void* d_ws,
                              size_t ws_size, hipStream_t stream) {
  (void)in_sizes; (void)n_in; (void)out_size; (void)ws_size;
  const float* x = (const float*)d_in[0];
  const float* h0 = (const float*)d_in[1];
  const float* c0 = (const float*)d_in[2];
  const float* W0 = (const float*)d_in[3];
  const float* R0 = (const float*)d_in[4];
  const float* bi0 = (const float*)d_in[5];
  const float* bh0 = (const float*)d_in[6];
  const float* W1 = (const float*)d_in[7];
  const float* R1 = (const float*)d_in[8];
  const float* bi1 = (const float*)d_in[9];
  const float* bh1 = (const float*)d_in[10];
  float* outp = (float*)d_out;

  // ws: Wbf0 8MB | Wp1 8MB | xg0p 128MB | hpp0 128KB | hpp1 128KB | flags
  char* ws = (char*)d_ws;
  ushort_t* Wbf0 = (ushort_t*)ws;
  ushort_t* Wp1 = (ushort_t*)(ws + 8388608);
  ushort_t* xg0p = (ushort_t*)(ws + 16777216);
  ushort_t* hpp0 = (ushort_t*)(ws + 16777216 + 134217728);
  ushort_t* hpp1 = (ushort_t*)((char*)hpp0 + 131072);
  uint_t* flags = (uint_t*)((char*)hpp1 + 131072);

  const int REC_LDS = 131072 + 32 * GL_P * 4;  // 135296 B
  (void)hipFuncSetAttribute((const void*)fused_rec,
                            hipFuncAttributeMaxDynamicSharedMemorySize,
                            REC_LDS);
  (void)hipMemsetAsync(flags, 0, NWG * sizeof(uint_t), stream);

  float* hfinb = outp + 16777216;  // [2][32][1024]
  float* cfinb = hfinb + 65536;    // [2][32][1024]

  cvt_f32_bf16<<<dim3(1024), dim3(256), 0, stream>>>(W0, Wbf0, 1048576);
  cvt_permW1<<<dim3(4096), dim3(256), 0, stream>>>(W1, Wp1);
  gemm_xg<<<dim3(128, 32), dim3(256), 0, stream>>>(x, Wbf0, bi0, xg0p);
  fused_rec<<<dim3(NWG), dim3(256), REC_LDS, stream>>>(
      xg0p, R0, R1, Wp1, bh0, bi1, bh1, h0, c0, outp, hfinb, cfinb,
      hpp0, hpp1, flags);
}

// Round 9
// 7896.107 us; speedup vs baseline: 1.0998x; 1.0998x over previous
//
#include <hip/hip_runtime.h>

typedef unsigned short ushort_t;
typedef unsigned int uint_t;
typedef __bf16 bf16x8 __attribute__((ext_vector_type(8)));
typedef float f32x4 __attribute__((ext_vector_type(4)));

#define T_STEPS 512
#define NWG 256
#define GL_P 33  // gate-tile stride in f32

union bfu { uint4 u; bf16x8 v; };

__device__ __forceinline__ float bf2f(ushort_t u) {
  union { unsigned u; float f; } v; v.u = ((unsigned)u) << 16; return v.f;
}
__device__ __forceinline__ ushort_t f2bf(float f) {
  union { float f; unsigned u; } v; v.f = f;
  unsigned r = (v.u + 0x7FFFu + ((v.u >> 16) & 1u)) >> 16;
  return (ushort_t)r;
}
__device__ __forceinline__ uint_t pack2(float a, float b) {
  return (uint_t)f2bf(a) | ((uint_t)f2bf(b) << 16);
}
__device__ __forceinline__ float sigf(float x) {
  return 1.0f / (1.0f + __expf(-x));
}

// ---------------------------------------------------------------------------
// fp32 -> bf16, vectorized, grid-stride
// ---------------------------------------------------------------------------
__global__ void __launch_bounds__(256) cvt_f32_bf16(
    const float* __restrict__ in, ushort_t* __restrict__ outp, int n4) {
  int i = blockIdx.x * 256 + threadIdx.x;
  const int stride = gridDim.x * 256;
  for (; i < n4; i += stride) {
    float4 v = ((const float4*)in)[i];
    ushort4 o;
    o.x = f2bf(v.x); o.y = f2bf(v.y); o.z = f2bf(v.z); o.w = f2bf(v.w);
    ((ushort4*)outp)[i] = o;
  }
}

// ---------------------------------------------------------------------------
// init: h0_all (fp32 [2][32][1024]) -> slot 1 of hpp0/hpp1 (bf16)
// ---------------------------------------------------------------------------
__global__ void __launch_bounds__(256) init_h(
    const float* __restrict__ h0_all, ushort_t* __restrict__ hpp0,
    ushort_t* __restrict__ hpp1) {
  int i = blockIdx.x * 256 + threadIdx.x;  // 16384 threads x float4
  int l = i >> 13, j = i & 8191;
  float4 v = ((const float4*)(h0_all + l * 32768))[j];
  ushort4 o;
  o.x = f2bf(v.x); o.y = f2bf(v.y); o.z = f2bf(v.z); o.w = f2bf(v.w);
  ((ushort4*)((l ? hpp1 : hpp0) + 32768))[j] = o;
}

// ---------------------------------------------------------------------------
// GEMM: xg0p[m][pc] = sum_k X[m][k]*W0[n][k] + bi0[n], column-permuted
// pc = ((n&1023)>>3)*32 + (n&7)*4 + (n>>10).  X fp32 (reg-staged cvt), W bf16.
// ---------------------------------------------------------------------------
__global__ void __launch_bounds__(256, 1) gemm_xg(
    const float* __restrict__ X, const ushort_t* __restrict__ Wm,
    const float* __restrict__ bi, ushort_t* __restrict__ outp) {
  __shared__ char smem[65536];
  const int tid = threadIdx.x;
  const int lane = tid & 63, w = tid >> 6;
  const int m0 = blockIdx.x * 128, n0 = blockIdx.y * 128;
  const int wr = w >> 1, wc = w & 1;
  const int lr = lane & 15, kg = lane >> 4;
  const int ar_ = tid & 127;
  const int abq = (tid >> 7) * 4;

  f32x4 acc[4][4] = {};
  float4 fa[8];

  auto stageA_issue = [&](int kt) {
    const float* src = X + (size_t)(m0 + ar_) * 1024 + kt * 64 + abq * 8;
#pragma unroll
    for (int i = 0; i < 4; ++i) {
      fa[2 * i] = *(const float4*)(src + i * 8);
      fa[2 * i + 1] = *(const float4*)(src + i * 8 + 4);
    }
  };
  auto stageA_write = [&](int p) {
    char* sA = smem + p * 32768;
#pragma unroll
    for (int i = 0; i < 4; ++i) {
      int blk = abq + i;
      uint4 o;
      o.x = pack2(fa[2 * i].x, fa[2 * i].y);
      o.y = pack2(fa[2 * i].z, fa[2 * i].w);
      o.z = pack2(fa[2 * i + 1].x, fa[2 * i + 1].y);
      o.w = pack2(fa[2 * i + 1].z, fa[2 * i + 1].w);
      *(uint4*)(sA + ar_ * 128 + ((blk ^ (ar_ & 7)) << 4)) = o;
    }
  };
  auto stageB = [&](int kt, int p) {
    const int ks = kt * 64;
    char* sB = smem + p * 32768 + 16384;
#pragma unroll
    for (int i = 0; i < 4; ++i) {
      int wi = w * 4 + i;
      int e = wi * 64 + lane;
      int row = e >> 3, pb = e & 7;
      int kb = pb ^ (row & 7);
      const ushort_t* gB = Wm + (size_t)(n0 + row) * 1024 + ks + kb * 8;
      __builtin_amdgcn_global_load_lds(
          (const __attribute__((address_space(1))) void*)gB,
          (__attribute__((address_space(3))) void*)(sB + wi * 1024), 16, 0, 0);
    }
  };

  stageA_issue(0);
  stageB(0, 0);
  stageA_write(0);
  __syncthreads();
#pragma unroll 1
  for (int kt = 0; kt < 16; ++kt) {
    const int p = kt & 1;
    if (kt < 15) { stageA_issue(kt + 1); stageB(kt + 1, p ^ 1); }
    const char* sA = smem + p * 32768;
    const char* sB = sA + 16384;
#pragma unroll
    for (int k2 = 0; k2 < 2; ++k2) {
      bf16x8 af[4], bf[4];
#pragma unroll
      for (int mt = 0; mt < 4; ++mt) {
        int ar = wr * 64 + mt * 16 + lr;
        int kb = k2 * 4 + kg;
        af[mt] = *(const bf16x8*)(sA + ar * 128 + ((kb ^ (ar & 7)) << 4));
      }
#pragma unroll
      for (int nt = 0; nt < 4; ++nt) {
        int br = wc * 64 + nt * 16 + lr;
        int kb = k2 * 4 + kg;
        bf[nt] = *(const bf16x8*)(sB + br * 128 + ((kb ^ (br & 7)) << 4));
      }
#pragma unroll
      for (int mt = 0; mt < 4; ++mt)
#pragma unroll
        for (int nt = 0; nt < 4; ++nt)
          acc[mt][nt] = __builtin_amdgcn_mfma_f32_16x16x32_bf16(
              af[mt], bf[nt], acc[mt][nt], 0, 0, 0);
    }
    if (kt < 15) stageA_write(p ^ 1);
    __syncthreads();
  }
#pragma unroll
  for (int nt = 0; nt < 4; ++nt) {
    int gc = n0 + wc * 64 + nt * 16 + lr;
    int pc = ((gc & 1023) >> 3) * 32 + (gc & 7) * 4 + (gc >> 10);
    float bv = bi[gc];
#pragma unroll
    for (int mt = 0; mt < 4; ++mt) {
#pragma unroll
      for (int r = 0; r < 4; ++r) {
        int gr = m0 + wr * 64 + mt * 16 + kg * 4 + r;
        outp[(size_t)gr * 4096 + pc] = f2bf(acc[mt][nt][r] + bv);
      }
    }
  }
}

// ---------------------------------------------------------------------------
// Fused 2-layer wavefront recurrence, transposed MFMA orientation:
//   D[gate_col][batch] = sum_k W[col][k] * h[batch][k]
// A = weights in LDS (XOR-swizzled; layer-1 = [R1|W1], K=2048 single pass).
// B = h fragments read DIRECTLY from hpp via batched sc0/sc1 loads,
// software-pipelined with counted vmcnt(8) (2 batches in flight).
// gates i,o,z,f:  c = c*f + z - i;  h = sig(c) - o.
// ---------------------------------------------------------------------------
#define GLD(dst, p, OFF)                                                  \
  asm volatile("global_load_dwordx4 %0, %1, off offset:" #OFF " sc0 sc1" \
               : "=v"(dst) : "v"(p))
#define ISSUE8(B, p)                                                      \
  do {                                                                    \
    GLD(B[0].u, (p), 0);   GLD(B[1].u, (p), 64);                          \
    GLD(B[2].u, (p), 128); GLD(B[3].u, (p), 192);                         \
    GLD(B[4].u, (p), 256); GLD(B[5].u, (p), 320);                         \
    GLD(B[6].u, (p), 384); GLD(B[7].u, (p), 448);                         \
  } while (0)
#define WAITN(N)                                                          \
  do {                                                                    \
    asm volatile("s_waitcnt vmcnt(" #N ")" ::: "memory");                 \
    __builtin_amdgcn_sched_barrier(0);                                    \
  } while (0)
#define MF(q, KT0, B)                                                     \
  {                                                                       \
    int kb_ = ((KT0) + (q)) * 4 + kg;                                     \
    bf16x8 a_ = *(const bf16x8*)(arow + ((kb_ ^ rx) << 4));               \
    if ((((KT0) + (q)) & 1) == 0)                                         \
      acc0 = __builtin_amdgcn_mfma_f32_16x16x32_bf16(a_, B[q].v, acc0,    \
                                                     0, 0, 0);            \
    else                                                                  \
      acc1 = __builtin_amdgcn_mfma_f32_16x16x32_bf16(a_, B[q].v, acc1,    \
                                                     0, 0, 0);            \
  }
#define CONSUME8(B, KT0)                                                  \
  MF(0, KT0, B) MF(1, KT0, B) MF(2, KT0, B) MF(3, KT0, B)                 \
  MF(4, KT0, B) MF(5, KT0, B) MF(6, KT0, B) MF(7, KT0, B)

__global__ void __launch_bounds__(256, 1) fused_rec(
    const ushort_t* __restrict__ xg0p, const float* __restrict__ R0,
    const float* __restrict__ R1, const float* __restrict__ W1,
    const float* __restrict__ bh0, const float* __restrict__ bi1,
    const float* __restrict__ bh1, const float* __restrict__ c0_all,
    float* __restrict__ out_f, float* __restrict__ hfinb,
    float* __restrict__ cfinb, ushort_t* __restrict__ hpp0,
    ushort_t* __restrict__ hpp1, uint_t* __restrict__ flags) {
  extern __shared__ char smem[];
  char* wl = smem;                      // [32 cols][4096 B] swizzled weights
  float* gl = (float*)(smem + 131072);  // [32][GL_P] f32

  const int tid = threadIdx.x;
  const int wg = blockIdx.x;
  const int layer = wg >> 7;
  const int wgl = wg & 127;
  const int j0 = wgl * 8;
  const int lane = tid & 63, w = tid >> 6;
  const int mt16 = (w >> 1) << 4, nt16 = (w & 1) << 4;
  const int lr16 = lane & 15, kg = lane >> 4;
  const int b = tid >> 3, jj = tid & 7;
  const int rx = lr16 & 7;

  // ---- one-time: weights -> LDS (cvt fp32->bf16, XOR-swizzled) ----
  // LDS row c (0..31): gate c>>3, hidden j0+(c&7); k-blocks kb (16B each).
  if (layer == 0) {
#pragma unroll 2
    for (int it = 0; it < 16; ++it) {
      int idx = it * 256 + tid;
      int row = idx >> 7, kb = idx & 127;
      int wrr = ((row >> 3) << 10) + j0 + (row & 7);
      const float* src = R0 + (size_t)wrr * 1024 + kb * 8;
      float4 f0 = *(const float4*)src;
      float4 f1 = *(const float4*)(src + 4);
      uint4 o;
      o.x = pack2(f0.x, f0.y); o.y = pack2(f0.z, f0.w);
      o.z = pack2(f1.x, f1.y); o.w = pack2(f1.z, f1.w);
      *(uint4*)(wl + row * 4096 + ((kb ^ (row & 7)) << 4)) = o;
    }
  } else {
#pragma unroll 2
    for (int it = 0; it < 32; ++it) {
      int idx = it * 256 + tid;
      int row = idx >> 8, kb = idx & 255;
      int wrr = ((row >> 3) << 10) + j0 + (row & 7);
      const float* src = (kb < 128)
                             ? (R1 + (size_t)wrr * 1024 + kb * 8)
                             : (W1 + (size_t)wrr * 1024 + (kb - 128) * 8);
      float4 f0 = *(const float4*)src;
      float4 f1 = *(const float4*)(src + 4);
      uint4 o;
      o.x = pack2(f0.x, f0.y); o.y = pack2(f0.z, f0.w);
      o.z = pack2(f1.x, f1.y); o.w = pack2(f1.z, f1.w);
      *(uint4*)(wl + row * 4096 + ((kb ^ (row & 7)) << 4)) = o;
    }
  }

  float bhv[4];
#pragma unroll
  for (int g = 0; g < 4; ++g) {
    int gi = g * 1024 + j0 + jj;
    bhv[g] = layer ? (bi1[gi] + bh1[gi]) : bh0[gi];
  }
  const int cidx = b * 1024 + j0 + jj;
  float c_st = c0_all[layer * 32768 + cidx];
  uint_t* hppd = (uint_t*)(layer ? hpp1 : hpp0);
  const char* arow = wl + (mt16 + lr16) * 4096;
  __syncthreads();

#pragma unroll 1
  for (int s = 0; s <= T_STEPS; ++s) {
    const bool active = layer ? (s >= 1) : (s < T_STEPS);
    if (active) {
      const int t = layer ? (s - 1) : s;
      uint2 xgu = {0, 0};
      if (layer == 0)
        xgu = *(const uint2*)(xg0p + ((size_t)t * 32 + b) * 4096 +
                              wgl * 32 + jj * 4);
      f32x4 acc0 = {0.f, 0.f, 0.f, 0.f}, acc1 = {0.f, 0.f, 0.f, 0.f};
      // B lane base: batch row (nt16+lr16), k-group kg
      const int lboff = (nt16 + lr16) * 2048 + kg * 16;
      if (layer == 0) {
        const char* pA =
            (const char*)hpp0 + (((t + 1) & 1) << 16) + lboff;
        bfu bA[8], bB[8];
        ISSUE8(bA, pA);
        ISSUE8(bB, pA + 512);
        WAITN(8); CONSUME8(bA, 0);  ISSUE8(bA, pA + 1024);
        WAITN(8); CONSUME8(bB, 8);  ISSUE8(bB, pA + 1536);
        WAITN(8); CONSUME8(bA, 16);
        WAITN(0); CONSUME8(bB, 24);
      } else {
        const char* pA =
            (const char*)hpp1 + (((t + 1) & 1) << 16) + lboff;  // h1(t-1)
        const char* pB =
            (const char*)hpp0 + ((t & 1) << 16) + lboff;        // h0(t)
        bfu bA[8], bB[8];
        ISSUE8(bA, pA);
        ISSUE8(bB, pA + 512);
        WAITN(8); CONSUME8(bA, 0);   ISSUE8(bA, pA + 1024);
        WAITN(8); CONSUME8(bB, 8);   ISSUE8(bB, pA + 1536);
        WAITN(8); CONSUME8(bA, 16);  ISSUE8(bA, pB);
        WAITN(8); CONSUME8(bB, 24);  ISSUE8(bB, pB + 512);
        WAITN(8); CONSUME8(bA, 32);  ISSUE8(bA, pB + 1024);
        WAITN(8); CONSUME8(bB, 40);  ISSUE8(bB, pB + 1536);
        WAITN(8); CONSUME8(bA, 48);
        WAITN(0); CONSUME8(bB, 56);
      }
      f32x4 acc = acc0 + acc1;
      // D: lane holds D[row=(lane>>4)*4+r][col=lane&15]; row=gatecol, col=batch
#pragma unroll
      for (int r = 0; r < 4; ++r)
        gl[(mt16 + kg * 4 + r) * GL_P + nt16 + lr16] = acc[r];
      __syncthreads();

      float pre0 = gl[(0 + jj) * GL_P + b] + bhv[0];
      float pre1 = gl[(8 + jj) * GL_P + b] + bhv[1];
      float pre2 = gl[(16 + jj) * GL_P + b] + bhv[2];
      float pre3 = gl[(24 + jj) * GL_P + b] + bhv[3];
      if (layer == 0) {
        pre0 += bf2f((ushort_t)(xgu.x & 0xffff));
        pre1 += bf2f((ushort_t)(xgu.x >> 16));
        pre2 += bf2f((ushort_t)(xgu.y & 0xffff));
        pre3 += bf2f((ushort_t)(xgu.y >> 16));
      }
      float ig = sigf(pre0), og = sigf(pre1), zg = sigf(pre2), fg = sigf(pre3);
      c_st = c_st * fg + zg - ig;
      float hv = sigf(c_st) - og;
      if (layer) out_f[(size_t)t * 32768 + cidx] = hv;

      // publish h(t): packed bf16 pair, L3-coherent
      ushort_t hb = f2bf(hv);
      int partner = __shfl_down((int)hb, 1, 64);
      if ((tid & 1) == 0) {
        uint_t packed = (uint_t)hb | (((uint_t)(unsigned short)partner) << 16);
        uint_t* dst = hppd + (((t & 1) << 14) + (cidx >> 1));
        asm volatile("global_store_dword %0, %1, off sc0 sc1"
                     :: "v"(dst), "v"(packed) : "memory");
      }
      if (t == T_STEPS - 1) {
        hfinb[layer * 32768 + cidx] = hv;
        cfinb[layer * 32768 + cidx] = c_st;
      }
    }
    if (s < T_STEPS) {
      const uint_t gen1 = (uint_t)s + 1u;
      asm volatile("s_waitcnt vmcnt(0)" ::: "memory");
      __syncthreads();
      if (tid == 0)
        __hip_atomic_store(&flags[wg], gen1, __ATOMIC_RELAXED,
                           __HIP_MEMORY_SCOPE_AGENT);
      while (__hip_atomic_load(&flags[tid], __ATOMIC_RELAXED,
                               __HIP_MEMORY_SCOPE_AGENT) < gen1) {
        __builtin_amdgcn_s_sleep(1);
      }
      __syncthreads();
      asm volatile("" ::: "memory");
    }
  }
}

// ---------------------------------------------------------------------------
extern "C" void kernel_launch(void* const* d_in, const int* in_sizes, int n_in,
                              void* d_out, int out_size, void* d_ws,
                              size_t ws_size, hipStream_t stream) {
  (void)in_sizes; (void)n_in; (void)out_size; (void)ws_size;
  const float* x = (const float*)d_in[0];
  const float* h0 = (const float*)d_in[1];
  const float* c0 = (const float*)d_in[2];
  const float* W0 = (const float*)d_in[3];
  const float* R0 = (const float*)d_in[4];
  const float* bi0 = (const float*)d_in[5];
  const float* bh0 = (const float*)d_in[6];
  const float* W1 = (const float*)d_in[7];
  const float* R1 = (const float*)d_in[8];
  const float* bi1 = (const float*)d_in[9];
  const float* bh1 = (const float*)d_in[10];
  float* outp = (float*)d_out;

  // ws: Wbf0 8MB | xg0p 128MB | hpp0 128KB | hpp1 128KB | flags
  char* ws = (char*)d_ws;
  ushort_t* Wbf0 = (ushort_t*)ws;
  ushort_t* xg0p = (ushort_t*)(ws + 8388608);
  ushort_t* hpp0 = (ushort_t*)(ws + 8388608 + 134217728);
  ushort_t* hpp1 = (ushort_t*)((char*)hpp0 + 131072);
  uint_t* flags = (uint_t*)((char*)hpp1 + 131072);

  const int REC_LDS = 131072 + 32 * GL_P * 4;  // 135296 B
  (void)hipFuncSetAttribute((const void*)fused_rec,
                            hipFuncAttributeMaxDynamicSharedMemorySize,
                            REC_LDS);
  (void)hipMemsetAsync(flags, 0, NWG * sizeof(uint_t), stream);

  float* hfinb = outp + 16777216;  // [2][32][1024]
  float* cfinb = hfinb + 65536;    // [2][32][1024]

  cvt_f32_bf16<<<dim3(1024), dim3(256), 0, stream>>>(W0, Wbf0, 1048576);
  init_h<<<dim3(64), dim3(256), 0, stream>>>(h0, hpp0, hpp1);
  gemm_xg<<<dim3(128, 32), dim3(256), 0, stream>>>(x, Wbf0, bi0, xg0p);
  fused_rec<<<dim3(NWG), dim3(256), REC_LDS, stream>>>(
      xg0p, R0, R1, W1, bh0, bi1, bh1, c0, outp, hfinb, cfinb,
      hpp0, hpp1, flags);
}

// Round 10
// 4598.444 us; speedup vs baseline: 1.8885x; 1.7171x over previous
//
#include <hip/hip_runtime.h>

typedef unsigned short ushort_t;
typedef unsigned int uint_t;
typedef __bf16 bf16x8 __attribute__((ext_vector_type(8)));
typedef float f32x4 __attribute__((ext_vector_type(4)));

#define T_STEPS 512
#define NWG 256

union bfu { uint4 u; bf16x8 v; };

__device__ __forceinline__ float bf2f(ushort_t u) {
  union { unsigned u; float f; } v; v.u = ((unsigned)u) << 16; return v.f;
}
__device__ __forceinline__ ushort_t f2bf(float f) {
  union { float f; unsigned u; } v; v.f = f;
  unsigned r = (v.u + 0x7FFFu + ((v.u >> 16) & 1u)) >> 16;
  return (ushort_t)r;
}
__device__ __forceinline__ uint_t pack2(float a, float b) {
  return (uint_t)f2bf(a) | ((uint_t)f2bf(b) << 16);
}
__device__ __forceinline__ float sigf(float x) {
  return 1.0f / (1.0f + __expf(-x));
}

// ---------------------------------------------------------------------------
__global__ void __launch_bounds__(256) cvt_f32_bf16(
    const float* __restrict__ in, ushort_t* __restrict__ outp, int n4) {
  int i = blockIdx.x * 256 + threadIdx.x;
  const int stride = gridDim.x * 256;
  for (; i < n4; i += stride) {
    float4 v = ((const float4*)in)[i];
    ushort4 o;
    o.x = f2bf(v.x); o.y = f2bf(v.y); o.z = f2bf(v.z); o.w = f2bf(v.w);
    ((ushort4*)outp)[i] = o;
  }
}

// ---------------------------------------------------------------------------
// init: h0_all (fp32 [2][32][1024]) -> slot 1 of hpp0/hpp1 (bf16)
// ---------------------------------------------------------------------------
__global__ void __launch_bounds__(256) init_h(
    const float* __restrict__ h0_all, ushort_t* __restrict__ hpp0,
    ushort_t* __restrict__ hpp1) {
  int i = blockIdx.x * 256 + threadIdx.x;  // 16384 threads x float4
  int l = i >> 13, j = i & 8191;
  float4 v = ((const float4*)(h0_all + l * 32768))[j];
  ushort4 o;
  o.x = f2bf(v.x); o.y = f2bf(v.y); o.z = f2bf(v.z); o.w = f2bf(v.w);
  ((ushort4*)((l ? hpp1 : hpp0) + 32768))[j] = o;
}

// ---------------------------------------------------------------------------
// GEMM: xg0p[m][pc] = sum_k X[m][k]*W0[n][k] + bi0[n], column-permuted
// pc = ((n&1023)>>3)*32 + (n&7)*4 + (n>>10).  X fp32 (reg-staged cvt), W bf16.
// ---------------------------------------------------------------------------
__global__ void __launch_bounds__(256, 1) gemm_xg(
    const float* __restrict__ X, const ushort_t* __restrict__ Wm,
    const float* __restrict__ bi, ushort_t* __restrict__ outp) {
  __shared__ char smem[65536];
  const int tid = threadIdx.x;
  const int lane = tid & 63, w = tid >> 6;
  const int m0 = blockIdx.x * 128, n0 = blockIdx.y * 128;
  const int wr = w >> 1, wc = w & 1;
  const int lr = lane & 15, kg = lane >> 4;
  const int ar_ = tid & 127;
  const int abq = (tid >> 7) * 4;

  f32x4 acc[4][4] = {};
  float4 fa[8];

  auto stageA_issue = [&](int kt) {
    const float* src = X + (size_t)(m0 + ar_) * 1024 + kt * 64 + abq * 8;
#pragma unroll
    for (int i = 0; i < 4; ++i) {
      fa[2 * i] = *(const float4*)(src + i * 8);
      fa[2 * i + 1] = *(const float4*)(src + i * 8 + 4);
    }
  };
  auto stageA_write = [&](int p) {
    char* sA = smem + p * 32768;
#pragma unroll
    for (int i = 0; i < 4; ++i) {
      int blk = abq + i;
      uint4 o;
      o.x = pack2(fa[2 * i].x, fa[2 * i].y);
      o.y = pack2(fa[2 * i].z, fa[2 * i].w);
      o.z = pack2(fa[2 * i + 1].x, fa[2 * i + 1].y);
      o.w = pack2(fa[2 * i + 1].z, fa[2 * i + 1].w);
      *(uint4*)(sA + ar_ * 128 + ((blk ^ (ar_ & 7)) << 4)) = o;
    }
  };
  auto stageB = [&](int kt, int p) {
    const int ks = kt * 64;
    char* sB = smem + p * 32768 + 16384;
#pragma unroll
    for (int i = 0; i < 4; ++i) {
      int wi = w * 4 + i;
      int e = wi * 64 + lane;
      int row = e >> 3, pb = e & 7;
      int kb = pb ^ (row & 7);
      const ushort_t* gB = Wm + (size_t)(n0 + row) * 1024 + ks + kb * 8;
      __builtin_amdgcn_global_load_lds(
          (const __attribute__((address_space(1))) void*)gB,
          (__attribute__((address_space(3))) void*)(sB + wi * 1024), 16, 0, 0);
    }
  };

  stageA_issue(0);
  stageB(0, 0);
  stageA_write(0);
  __syncthreads();
#pragma unroll 1
  for (int kt = 0; kt < 16; ++kt) {
    const int p = kt & 1;
    if (kt < 15) { stageA_issue(kt + 1); stageB(kt + 1, p ^ 1); }
    const char* sA = smem + p * 32768;
    const char* sB = sA + 16384;
#pragma unroll
    for (int k2 = 0; k2 < 2; ++k2) {
      bf16x8 af[4], bf[4];
#pragma unroll
      for (int mt = 0; mt < 4; ++mt) {
        int ar = wr * 64 + mt * 16 + lr;
        int kb = k2 * 4 + kg;
        af[mt] = *(const bf16x8*)(sA + ar * 128 + ((kb ^ (ar & 7)) << 4));
      }
#pragma unroll
      for (int nt = 0; nt < 4; ++nt) {
        int br = wc * 64 + nt * 16 + lr;
        int kb = k2 * 4 + kg;
        bf[nt] = *(const bf16x8*)(sB + br * 128 + ((kb ^ (br & 7)) << 4));
      }
#pragma unroll
      for (int mt = 0; mt < 4; ++mt)
#pragma unroll
        for (int nt = 0; nt < 4; ++nt)
          acc[mt][nt] = __builtin_amdgcn_mfma_f32_16x16x32_bf16(
              af[mt], bf[nt], acc[mt][nt], 0, 0, 0);
    }
    if (kt < 15) stageA_write(p ^ 1);
    __syncthreads();
  }
#pragma unroll
  for (int nt = 0; nt < 4; ++nt) {
    int gc = n0 + wc * 64 + nt * 16 + lr;
    int pc = ((gc & 1023) >> 3) * 32 + (gc & 7) * 4 + (gc >> 10);
    float bv = bi[gc];
#pragma unroll
    for (int mt = 0; mt < 4; ++mt) {
#pragma unroll
      for (int r = 0; r < 4; ++r) {
        int gr = m0 + wr * 64 + mt * 16 + kg * 4 + r;
        outp[(size_t)gr * 4096 + pc] = f2bf(acc[mt][nt][r] + bv);
      }
    }
  }
}

// ---------------------------------------------------------------------------
// Fused 2-layer wavefront recurrence. 256 WGs x 512 thr (8 waves, 1 WG/CU).
// Wave w: gate-col half n16=(w&1)*16, K-quarter kq=w>>1. Weights live in
// 64 VGPRs/lane (layer1: K=2048 concat [R1|W1] split 4 ways). h staged once
// per WG into LDS via batched sc0/sc1 loads (one L3 round trip). K-partials
// reduced through gl[4][32][33] in LDS.  gates i,o,z,f:
//   c = c*f + z - i;  h = sig(c) - o.
// ---------------------------------------------------------------------------
#define GLD4(dst, addr)                                        \
  asm volatile("global_load_dwordx4 %0, %1, off sc0 sc1"      \
               : "=v"(dst) : "v"(addr))
#define WAITN(N)                                               \
  do {                                                         \
    asm volatile("s_waitcnt vmcnt(" #N ")" ::: "memory");      \
    __builtin_amdgcn_sched_barrier(0);                         \
  } while (0)

__global__ void __launch_bounds__(512, 1) fused_rec(
    const ushort_t* __restrict__ xg0p, const float* __restrict__ R0,
    const float* __restrict__ R1, const float* __restrict__ W1,
    const float* __restrict__ bh0, const float* __restrict__ bi1,
    const float* __restrict__ bh1, const float* __restrict__ c0_all,
    float* __restrict__ out_f, float* __restrict__ hfinb,
    float* __restrict__ cfinb, ushort_t* __restrict__ hpp0,
    ushort_t* __restrict__ hpp1, uint_t* __restrict__ flags) {
  extern __shared__ char smem[];
  char* hl = smem;                      // h1 [32][2048B] | h0 at +65536
  float* gl = (float*)(smem + 131072);  // [4][32][33] f32 partials

  const int tid = threadIdx.x;
  const int wg = blockIdx.x;
  const int layer = wg >> 7;
  const int wgl = wg & 127;
  const int j0 = wgl * 8;
  const int lane = tid & 63, w = tid >> 6;
  const int n16 = (w & 1) << 4;   // gate-col half
  const int kq = w >> 1;          // K quarter
  const int lr16 = lane & 15, kg = lane >> 4;
  const int b = (tid >> 3) & 31, jj = tid & 7;
  const int rx = lr16 & 7;

  // ---- one-time: weight fragments -> registers ----
  // lane's gate-col c: gate c>>3, hidden j0+(c&7); weight row = g*1024+j0+(c&7)
  const int c = n16 + lr16;
  const int r_w = ((c >> 3) << 10) + j0 + (c & 7);
  bf16x8 breg[16];
  if (layer == 0) {
#pragma unroll
    for (int i = 0; i < 8; ++i) {
      const float* src = R0 + (size_t)r_w * 1024 + kq * 256 + i * 32 + kg * 8;
      float4 f0 = *(const float4*)src;
      float4 f1 = *(const float4*)(src + 4);
      bfu o;
      o.u.x = pack2(f0.x, f0.y); o.u.y = pack2(f0.z, f0.w);
      o.u.z = pack2(f1.x, f1.y); o.u.w = pack2(f1.z, f1.w);
      breg[i] = o.v;
    }
  } else {
#pragma unroll
    for (int i = 0; i < 16; ++i) {
      int k = kq * 512 + i * 32 + kg * 8;
      const float* src = (k < 1024) ? (R1 + (size_t)r_w * 1024 + k)
                                    : (W1 + (size_t)r_w * 1024 + (k - 1024));
      float4 f0 = *(const float4*)src;
      float4 f1 = *(const float4*)(src + 4);
      bfu o;
      o.u.x = pack2(f0.x, f0.y); o.u.y = pack2(f0.z, f0.w);
      o.u.z = pack2(f1.x, f1.y); o.u.w = pack2(f1.z, f1.w);
      breg[i] = o.v;
    }
  }

  float bhv[4];
#pragma unroll
  for (int g = 0; g < 4; ++g) {
    int gi = g * 1024 + j0 + jj;
    bhv[g] = layer ? (bi1[gi] + bh1[gi]) : bh0[gi];
  }
  const int cidx = b * 1024 + j0 + jj;
  float c_st = c0_all[layer * 32768 + cidx];
  uint_t* hppd = (uint_t*)(layer ? hpp1 : hpp0);
  __syncthreads();

#pragma unroll 1
  for (int s = 0; s <= T_STEPS; ++s) {
    const bool active = layer ? (s >= 1) : (s < T_STEPS);
    if (active) {
      const int t = layer ? (s - 1) : s;
      uint2 xgu = {0, 0};
      uint4 hv[16];
      // ---- stage h -> LDS: batched sc loads, one L3 round trip ----
      if (layer == 0) {
        const char* xga = (const char*)xg0p +
            (((size_t)t * 32 + b) * 4096 + wgl * 32 + jj * 4) * 2;
        asm volatile("global_load_dwordx2 %0, %1, off"
                     : "=v"(xgu) : "v"(xga));
        const char* hsrc =
            (const char*)hpp0 + (((t + 1) & 1) << 16) + tid * 16;
#pragma unroll
        for (int l = 0; l < 8; ++l) GLD4(hv[l], hsrc + l * 8192);
        WAITN(0);
#pragma unroll
        for (int l = 0; l < 8; ++l) {
          int idx = l * 512 + tid;
          int row = idx >> 7, kb = idx & 127;
          *(uint4*)(hl + row * 2048 + ((kb ^ (row & 7)) << 4)) = hv[l];
        }
      } else {
        const char* h1src =
            (const char*)hpp1 + (((t + 1) & 1) << 16) + tid * 16;
        const char* h0src =
            (const char*)hpp0 + ((t & 1) << 16) + tid * 16;
#pragma unroll
        for (int l = 0; l < 8; ++l) GLD4(hv[l], h1src + l * 8192);
#pragma unroll
        for (int l = 0; l < 8; ++l) GLD4(hv[8 + l], h0src + l * 8192);
        WAITN(8);
#pragma unroll
        for (int l = 0; l < 8; ++l) {
          int idx = l * 512 + tid;
          int row = idx >> 7, kb = idx & 127;
          *(uint4*)(hl + row * 2048 + ((kb ^ (row & 7)) << 4)) = hv[l];
        }
        WAITN(0);
#pragma unroll
        for (int l = 0; l < 8; ++l) {
          int idx = l * 512 + tid;
          int row = idx >> 7, kb = idx & 127;
          *(uint4*)(hl + 65536 + row * 2048 + ((kb ^ (row & 7)) << 4)) =
              hv[8 + l];
        }
      }
      __syncthreads();

      // ---- MFMA: wave computes both batch-half tiles for its (n16, kq) ----
      f32x4 acc0 = {0.f, 0.f, 0.f, 0.f}, acc1 = {0.f, 0.f, 0.f, 0.f};
      if (layer == 0) {
        const char* a0 = hl + lr16 * 2048;
        const char* a1 = hl + (16 + lr16) * 2048;
#pragma unroll
        for (int i = 0; i < 8; ++i) {
          int kb = kq * 32 + i * 4 + kg;
          bf16x8 av0 = *(const bf16x8*)(a0 + ((kb ^ rx) << 4));
          bf16x8 av1 = *(const bf16x8*)(a1 + ((kb ^ rx) << 4));
          acc0 = __builtin_amdgcn_mfma_f32_16x16x32_bf16(av0, breg[i], acc0,
                                                         0, 0, 0);
          acc1 = __builtin_amdgcn_mfma_f32_16x16x32_bf16(av1, breg[i], acc1,
                                                         0, 0, 0);
        }
      } else {
        const char* buf = hl + ((kq >> 1) ? 65536 : 0);
        const char* a0 = buf + lr16 * 2048;
        const char* a1 = buf + (16 + lr16) * 2048;
#pragma unroll
        for (int i = 0; i < 16; ++i) {
          int kb = (kq & 1) * 64 + i * 4 + kg;
          bf16x8 av0 = *(const bf16x8*)(a0 + ((kb ^ rx) << 4));
          bf16x8 av1 = *(const bf16x8*)(a1 + ((kb ^ rx) << 4));
          acc0 = __builtin_amdgcn_mfma_f32_16x16x32_bf16(av0, breg[i], acc0,
                                                         0, 0, 0);
          acc1 = __builtin_amdgcn_mfma_f32_16x16x32_bf16(av1, breg[i], acc1,
                                                         0, 0, 0);
        }
      }
      // gl[kq][batch][gatecol] partials
#pragma unroll
      for (int r = 0; r < 4; ++r) {
        gl[(kq * 32 + kg * 4 + r) * 33 + n16 + lr16] = acc0[r];
        gl[(kq * 32 + 16 + kg * 4 + r) * 33 + n16 + lr16] = acc1[r];
      }
      __syncthreads();

      if (tid < 256) {
        float pre[4];
#pragma unroll
        for (int g = 0; g < 4; ++g) {
          int col = g * 8 + jj;
          pre[g] = gl[(0 * 32 + b) * 33 + col] + gl[(1 * 32 + b) * 33 + col] +
                   gl[(2 * 32 + b) * 33 + col] + gl[(3 * 32 + b) * 33 + col] +
                   bhv[g];
        }
        if (layer == 0) {
          pre[0] += bf2f((ushort_t)(xgu.x & 0xffff));
          pre[1] += bf2f((ushort_t)(xgu.x >> 16));
          pre[2] += bf2f((ushort_t)(xgu.y & 0xffff));
          pre[3] += bf2f((ushort_t)(xgu.y >> 16));
        }
        float ig = sigf(pre[0]), og = sigf(pre[1]);
        float zg = sigf(pre[2]), fg = sigf(pre[3]);
        c_st = c_st * fg + zg - ig;
        float hv_ = sigf(c_st) - og;
        if (layer) out_f[(size_t)t * 32768 + cidx] = hv_;

        ushort_t hb = f2bf(hv_);
        int partner = __shfl_down((int)hb, 1, 64);
        if ((tid & 1) == 0) {
          uint_t packed =
              (uint_t)hb | (((uint_t)(unsigned short)partner) << 16);
          uint_t* dst = hppd + (((t & 1) << 14) + (cidx >> 1));
          asm volatile("global_store_dword %0, %1, off sc0 sc1"
                       :: "v"(dst), "v"(packed) : "memory");
        }
        if (t == T_STEPS - 1) {
          hfinb[layer * 32768 + cidx] = hv_;
          cfinb[layer * 32768 + cidx] = c_st;
        }
      }
    }
    if (s < T_STEPS) {
      const uint_t gen1 = (uint_t)s + 1u;
      asm volatile("s_waitcnt vmcnt(0)" ::: "memory");
      __syncthreads();
      if (tid == 0)
        __hip_atomic_store(&flags[wg], gen1, __ATOMIC_RELAXED,
                           __HIP_MEMORY_SCOPE_AGENT);
      if (tid < NWG) {
        while (__hip_atomic_load(&flags[tid], __ATOMIC_RELAXED,
                                 __HIP_MEMORY_SCOPE_AGENT) < gen1) {
          __builtin_amdgcn_s_sleep(1);
        }
      }
      __syncthreads();
      asm volatile("" ::: "memory");
    }
  }
}

// ---------------------------------------------------------------------------
extern "C" void kernel_launch(void* const* d_in, const int* in_sizes, int n_in,
                              void* d_out, int out_size, void* d_ws,
                              size_t ws_size, hipStream_t stream) {
  (void)in_sizes; (void)n_in; (void)out_size; (void)ws_size;
  const float* x = (const float*)d_in[0];
  const float* h0 = (const float*)d_in[1];
  const float* c0 = (const float*)d_in[2];
  const float* W0 = (const float*)d_in[3];
  const float* R0 = (const float*)d_in[4];
  const float* bi0 = (const float*)d_in[5];
  const float* bh0 = (const float*)d_in[6];
  const float* W1 = (const float*)d_in[7];
  const float* R1 = (const float*)d_in[8];
  const float* bi1 = (const float*)d_in[9];
  const float* bh1 = (const float*)d_in[10];
  float* outp = (float*)d_out;

  // ws: Wbf0 8MB | xg0p 128MB | hpp0 128KB | hpp1 128KB | flags
  char* ws = (char*)d_ws;
  ushort_t* Wbf0 = (ushort_t*)ws;
  ushort_t* xg0p = (ushort_t*)(ws + 8388608);
  ushort_t* hpp0 = (ushort_t*)(ws + 8388608 + 134217728);
  ushort_t* hpp1 = (ushort_t*)((char*)hpp0 + 131072);
  uint_t* flags = (uint_t*)((char*)hpp1 + 131072);

  const int REC_LDS = 131072 + 4 * 32 * 33 * 4;  // 147968 B
  (void)hipFuncSetAttribute((const void*)fused_rec,
                            hipFuncAttributeMaxDynamicSharedMemorySize,
                            REC_LDS);
  (void)hipMemsetAsync(flags, 0, NWG * sizeof(uint_t), stream);

  float* hfinb = outp + 16777216;  // [2][32][1024]
  float* cfinb = hfinb + 65536;    // [2][32][1024]

  cvt_f32_bf16<<<dim3(1024), dim3(256), 0, stream>>>(W0, Wbf0, 1048576);
  init_h<<<dim3(64), dim3(256), 0, stream>>>(h0, hpp0, hpp1);
  gemm_xg<<<dim3(128, 32), dim3(256), 0, stream>>>(x, Wbf0, bi0, xg0p);
  fused_rec<<<dim3(NWG), dim3(512), REC_LDS, stream>>>(
      xg0p, R0, R1, W1, bh0, bi1, bh1, c0, outp, hfinb, cfinb,
      hpp0, hpp1, flags);
}

// Round 11
// 4424.752 us; speedup vs baseline: 1.9626x; 1.0393x over previous
//
#include <hip/hip_runtime.h>

typedef unsigned short ushort_t;
typedef unsigned int uint_t;
typedef __bf16 bf16x8 __attribute__((ext_vector_type(8)));
typedef float f32x4 __attribute__((ext_vector_type(4)));

#define T_STEPS 512
#define NWG 256

union bfu { uint4 u; bf16x8 v; };

__device__ __forceinline__ float bf2f(ushort_t u) {
  union { unsigned u; float f; } v; v.u = ((unsigned)u) << 16; return v.f;
}
__device__ __forceinline__ ushort_t f2bf(float f) {
  union { float f; unsigned u; } v; v.f = f;
  unsigned r = (v.u + 0x7FFFu + ((v.u >> 16) & 1u)) >> 16;
  return (ushort_t)r;
}
__device__ __forceinline__ uint_t pack2(float a, float b) {
  return (uint_t)f2bf(a) | ((uint_t)f2bf(b) << 16);
}
__device__ __forceinline__ float sigf(float x) {
  return 1.0f / (1.0f + __expf(-x));
}

// ---------------------------------------------------------------------------
__global__ void __launch_bounds__(256) cvt_f32_bf16(
    const float* __restrict__ in, ushort_t* __restrict__ outp, int n4) {
  int i = blockIdx.x * 256 + threadIdx.x;
  const int stride = gridDim.x * 256;
  for (; i < n4; i += stride) {
    float4 v = ((const float4*)in)[i];
    ushort4 o;
    o.x = f2bf(v.x); o.y = f2bf(v.y); o.z = f2bf(v.z); o.w = f2bf(v.w);
    ((ushort4*)outp)[i] = o;
  }
}

// ---------------------------------------------------------------------------
// init: h0_all (fp32 [2][32][1024]) -> hpp0 ring slot 3 / hpp1 slot 1 (bf16)
// ---------------------------------------------------------------------------
__global__ void __launch_bounds__(256) init_h(
    const float* __restrict__ h0_all, ushort_t* __restrict__ hpp0,
    ushort_t* __restrict__ hpp1) {
  int i = blockIdx.x * 256 + threadIdx.x;  // 16384 threads x float4
  int l = i >> 13, j = i & 8191;
  float4 v = ((const float4*)(h0_all + l * 32768))[j];
  ushort4 o;
  o.x = f2bf(v.x); o.y = f2bf(v.y); o.z = f2bf(v.z); o.w = f2bf(v.w);
  ((ushort4*)(l ? (hpp1 + 32768) : (hpp0 + 98304)))[j] = o;
}

// ---------------------------------------------------------------------------
// GEMM: xg0p[m][pc] = sum_k X[m][k]*W0[n][k] + bi0[n], column-permuted
// pc = ((n&1023)>>3)*32 + (n&7)*4 + (n>>10).  X fp32 (reg-staged cvt), W bf16.
// ---------------------------------------------------------------------------
__global__ void __launch_bounds__(256, 1) gemm_xg(
    const float* __restrict__ X, const ushort_t* __restrict__ Wm,
    const float* __restrict__ bi, ushort_t* __restrict__ outp) {
  __shared__ char smem[65536];
  const int tid = threadIdx.x;
  const int lane = tid & 63, w = tid >> 6;
  const int m0 = blockIdx.x * 128, n0 = blockIdx.y * 128;
  const int wr = w >> 1, wc = w & 1;
  const int lr = lane & 15, kg = lane >> 4;
  const int ar_ = tid & 127;
  const int abq = (tid >> 7) * 4;

  f32x4 acc[4][4] = {};
  float4 fa[8];

  auto stageA_issue = [&](int kt) {
    const float* src = X + (size_t)(m0 + ar_) * 1024 + kt * 64 + abq * 8;
#pragma unroll
    for (int i = 0; i < 4; ++i) {
      fa[2 * i] = *(const float4*)(src + i * 8);
      fa[2 * i + 1] = *(const float4*)(src + i * 8 + 4);
    }
  };
  auto stageA_write = [&](int p) {
    char* sA = smem + p * 32768;
#pragma unroll
    for (int i = 0; i < 4; ++i) {
      int blk = abq + i;
      uint4 o;
      o.x = pack2(fa[2 * i].x, fa[2 * i].y);
      o.y = pack2(fa[2 * i].z, fa[2 * i].w);
      o.z = pack2(fa[2 * i + 1].x, fa[2 * i + 1].y);
      o.w = pack2(fa[2 * i + 1].z, fa[2 * i + 1].w);
      *(uint4*)(sA + ar_ * 128 + ((blk ^ (ar_ & 7)) << 4)) = o;
    }
  };
  auto stageB = [&](int kt, int p) {
    const int ks = kt * 64;
    char* sB = smem + p * 32768 + 16384;
#pragma unroll
    for (int i = 0; i < 4; ++i) {
      int wi = w * 4 + i;
      int e = wi * 64 + lane;
      int row = e >> 3, pb = e & 7;
      int kb = pb ^ (row & 7);
      const ushort_t* gB = Wm + (size_t)(n0 + row) * 1024 + ks + kb * 8;
      __builtin_amdgcn_global_load_lds(
          (const __attribute__((address_space(1))) void*)gB,
          (__attribute__((address_space(3))) void*)(sB + wi * 1024), 16, 0, 0);
    }
  };

  stageA_issue(0);
  stageB(0, 0);
  stageA_write(0);
  __syncthreads();
#pragma unroll 1
  for (int kt = 0; kt < 16; ++kt) {
    const int p = kt & 1;
    if (kt < 15) { stageA_issue(kt + 1); stageB(kt + 1, p ^ 1); }
    const char* sA = smem + p * 32768;
    const char* sB = sA + 16384;
#pragma unroll
    for (int k2 = 0; k2 < 2; ++k2) {
      bf16x8 af[4], bf[4];
#pragma unroll
      for (int mt = 0; mt < 4; ++mt) {
        int ar = wr * 64 + mt * 16 + lr;
        int kb = k2 * 4 + kg;
        af[mt] = *(const bf16x8*)(sA + ar * 128 + ((kb ^ (ar & 7)) << 4));
      }
#pragma unroll
      for (int nt = 0; nt < 4; ++nt) {
        int br = wc * 64 + nt * 16 + lr;
        int kb = k2 * 4 + kg;
        bf[nt] = *(const bf16x8*)(sB + br * 128 + ((kb ^ (br & 7)) << 4));
      }
#pragma unroll
      for (int mt = 0; mt < 4; ++mt)
#pragma unroll
        for (int nt = 0; nt < 4; ++nt)
          acc[mt][nt] = __builtin_amdgcn_mfma_f32_16x16x32_bf16(
              af[mt], bf[nt], acc[mt][nt], 0, 0, 0);
    }
    if (kt < 15) stageA_write(p ^ 1);
    __syncthreads();
  }
#pragma unroll
  for (int nt = 0; nt < 4; ++nt) {
    int gc = n0 + wc * 64 + nt * 16 + lr;
    int pc = ((gc & 1023) >> 3) * 32 + (gc & 7) * 4 + (gc >> 10);
    float bv = bi[gc];
#pragma unroll
    for (int mt = 0; mt < 4; ++mt) {
#pragma unroll
      for (int r = 0; r < 4; ++r) {
        int gr = m0 + wr * 64 + mt * 16 + kg * 4 + r;
        outp[(size_t)gr * 4096 + pc] = f2bf(acc[mt][nt][r] + bv);
      }
    }
  }
}

// ---------------------------------------------------------------------------
// Fused 2-layer wavefront recurrence with DECOUPLED group barriers.
// 256 WGs x 512 thr. WGs 0..127 = layer 0, 128..255 = layer 1.
// Layer 0 publishes h0(t) into a 4-slot ring (may run ~4 steps ahead;
// WAR credit: flags1 >= t-3). Layer 1 waits flags0 >= t+1 (usually
// pre-satisfied) + own flags1 >= t. Each group's barrier spans 128 WGs.
// Weights in VGPRs; h staged to LDS via batched sc0/sc1 loads.
// gates i,o,z,f:  c = c*f + z - i;  h = sig(c) - o.
// ---------------------------------------------------------------------------
#define GLD4(dst, addr)                                        \
  asm volatile("global_load_dwordx4 %0, %1, off sc0 sc1"      \
               : "=v"(dst) : "v"(addr))
#define WAITN(N)                                               \
  do {                                                         \
    asm volatile("s_waitcnt vmcnt(" #N ")" ::: "memory");      \
    __builtin_amdgcn_sched_barrier(0);                         \
  } while (0)

__global__ void __launch_bounds__(512, 1) fused_rec(
    const ushort_t* __restrict__ xg0p, const float* __restrict__ R0,
    const float* __restrict__ R1, const float* __restrict__ W1,
    const float* __restrict__ bh0, const float* __restrict__ bi1,
    const float* __restrict__ bh1, const float* __restrict__ c0_all,
    float* __restrict__ out_f, float* __restrict__ hfinb,
    float* __restrict__ cfinb, ushort_t* __restrict__ hpp0,
    ushort_t* __restrict__ hpp1, uint_t* __restrict__ flags0,
    uint_t* __restrict__ flags1) {
  extern __shared__ char smem[];
  char* hl = smem;                      // h1 [32][2048B] | h0 at +65536
  float* gl = (float*)(smem + 131072);  // [4][32][33] f32 partials

  const int tid = threadIdx.x;
  const int wg = blockIdx.x;
  const int layer = wg >> 7;
  const int wgl = wg & 127;
  const int j0 = wgl * 8;
  const int lane = tid & 63, w = tid >> 6;
  const int n16 = (w & 1) << 4;   // gate-col half
  const int kq = w >> 1;          // K quarter
  const int lr16 = lane & 15, kg = lane >> 4;
  const int b = (tid >> 3) & 31, jj = tid & 7;
  const int rx = lr16 & 7;

  uint_t* fown = layer ? flags1 : flags0;
  uint_t* foth = layer ? flags0 : flags1;

  // ---- one-time: weight fragments -> registers ----
  const int c = n16 + lr16;
  const int r_w = ((c >> 3) << 10) + j0 + (c & 7);
  bf16x8 breg[16];
  if (layer == 0) {
#pragma unroll
    for (int i = 0; i < 8; ++i) {
      const float* src = R0 + (size_t)r_w * 1024 + kq * 256 + i * 32 + kg * 8;
      float4 f0 = *(const float4*)src;
      float4 f1 = *(const float4*)(src + 4);
      bfu o;
      o.u.x = pack2(f0.x, f0.y); o.u.y = pack2(f0.z, f0.w);
      o.u.z = pack2(f1.x, f1.y); o.u.w = pack2(f1.z, f1.w);
      breg[i] = o.v;
    }
  } else {
#pragma unroll
    for (int i = 0; i < 16; ++i) {
      int k = kq * 512 + i * 32 + kg * 8;
      const float* src = (k < 1024) ? (R1 + (size_t)r_w * 1024 + k)
                                    : (W1 + (size_t)r_w * 1024 + (k - 1024));
      float4 f0 = *(const float4*)src;
      float4 f1 = *(const float4*)(src + 4);
      bfu o;
      o.u.x = pack2(f0.x, f0.y); o.u.y = pack2(f0.z, f0.w);
      o.u.z = pack2(f1.x, f1.y); o.u.w = pack2(f1.z, f1.w);
      breg[i] = o.v;
    }
  }

  float bhv[4];
#pragma unroll
  for (int g = 0; g < 4; ++g) {
    int gi = g * 1024 + j0 + jj;
    bhv[g] = layer ? (bi1[gi] + bh1[gi]) : bh0[gi];
  }
  const int cidx = b * 1024 + j0 + jj;
  float c_st = c0_all[layer * 32768 + cidx];
  uint_t* hppd = (uint_t*)(layer ? hpp1 : hpp0);

  // xg double-buffer (layer 0 only); per-t stride = 32*4096*2 bytes
  const char* xgbase = (const char*)xg0p +
      ((size_t)b * 4096 + (size_t)wgl * 32 + (size_t)jj * 4) * 2;
  uint2 xgu = {0, 0}, xgn = {0, 0};
  if (layer == 0)
    asm volatile("global_load_dwordx2 %0, %1, off" : "=v"(xgu) : "v"(xgbase));
  __syncthreads();

#pragma unroll 1
  for (int t = 0; t < T_STEPS; ++t) {
    // ---- wait phase: own-group barrier + cross-group check ----
    {
      const int genOwn = t;
      const int genOth = layer ? (t + 1) : (t - 3);
      if (tid < 128) {
        while ((int)__hip_atomic_load(&fown[tid], __ATOMIC_RELAXED,
                                      __HIP_MEMORY_SCOPE_AGENT) < genOwn)
          __builtin_amdgcn_s_sleep(1);
      } else if (tid < 256) {
        while ((int)__hip_atomic_load(&foth[tid - 128], __ATOMIC_RELAXED,
                                      __HIP_MEMORY_SCOPE_AGENT) < genOth)
          __builtin_amdgcn_s_sleep(1);
      }
      __syncthreads();
      asm volatile("" ::: "memory");
    }

    uint4 hv[16];
    if (layer == 0) {
      if (t + 1 < T_STEPS)
        asm volatile("global_load_dwordx2 %0, %1, off"
                     : "=v"(xgn) : "v"(xgbase + (size_t)(t + 1) * 262144));
      const char* hsrc =
          (const char*)hpp0 + (((t + 3) & 3) << 16) + tid * 16;
#pragma unroll
      for (int l = 0; l < 8; ++l) GLD4(hv[l], hsrc + l * 8192);
      WAITN(0);
#pragma unroll
      for (int l = 0; l < 8; ++l) {
        int idx = l * 512 + tid;
        int row = idx >> 7, kb = idx & 127;
        *(uint4*)(hl + row * 2048 + ((kb ^ (row & 7)) << 4)) = hv[l];
      }
    } else {
      const char* h1src =
          (const char*)hpp1 + (((t + 1) & 1) << 16) + tid * 16;
      const char* h0src =
          (const char*)hpp0 + ((t & 3) << 16) + tid * 16;
#pragma unroll
      for (int l = 0; l < 8; ++l) GLD4(hv[l], h1src + l * 8192);
#pragma unroll
      for (int l = 0; l < 8; ++l) GLD4(hv[8 + l], h0src + l * 8192);
      WAITN(8);
#pragma unroll
      for (int l = 0; l < 8; ++l) {
        int idx = l * 512 + tid;
        int row = idx >> 7, kb = idx & 127;
        *(uint4*)(hl + row * 2048 + ((kb ^ (row & 7)) << 4)) = hv[l];
      }
      WAITN(0);
#pragma unroll
      for (int l = 0; l < 8; ++l) {
        int idx = l * 512 + tid;
        int row = idx >> 7, kb = idx & 127;
        *(uint4*)(hl + 65536 + row * 2048 + ((kb ^ (row & 7)) << 4)) =
            hv[8 + l];
      }
    }
    __syncthreads();

    // ---- MFMA: wave computes both batch-half tiles for its (n16, kq) ----
    f32x4 acc0 = {0.f, 0.f, 0.f, 0.f}, acc1 = {0.f, 0.f, 0.f, 0.f};
    if (layer == 0) {
      const char* a0 = hl + lr16 * 2048;
      const char* a1 = hl + (16 + lr16) * 2048;
#pragma unroll
      for (int i = 0; i < 8; ++i) {
        int kb = kq * 32 + i * 4 + kg;
        bf16x8 av0 = *(const bf16x8*)(a0 + ((kb ^ rx) << 4));
        bf16x8 av1 = *(const bf16x8*)(a1 + ((kb ^ rx) << 4));
        acc0 = __builtin_amdgcn_mfma_f32_16x16x32_bf16(av0, breg[i], acc0,
                                                       0, 0, 0);
        acc1 = __builtin_amdgcn_mfma_f32_16x16x32_bf16(av1, breg[i], acc1,
                                                       0, 0, 0);
      }
    } else {
      const char* buf = hl + ((kq >> 1) ? 65536 : 0);
      const char* a0 = buf + lr16 * 2048;
      const char* a1 = buf + (16 + lr16) * 2048;
#pragma unroll
      for (int i = 0; i < 16; ++i) {
        int kb = (kq & 1) * 64 + i * 4 + kg;
        bf16x8 av0 = *(const bf16x8*)(a0 + ((kb ^ rx) << 4));
        bf16x8 av1 = *(const bf16x8*)(a1 + ((kb ^ rx) << 4));
        acc0 = __builtin_amdgcn_mfma_f32_16x16x32_bf16(av0, breg[i], acc0,
                                                       0, 0, 0);
        acc1 = __builtin_amdgcn_mfma_f32_16x16x32_bf16(av1, breg[i], acc1,
                                                       0, 0, 0);
      }
    }
#pragma unroll
    for (int r = 0; r < 4; ++r) {
      gl[(kq * 32 + kg * 4 + r) * 33 + n16 + lr16] = acc0[r];
      gl[(kq * 32 + 16 + kg * 4 + r) * 33 + n16 + lr16] = acc1[r];
    }
    __syncthreads();

    if (tid < 256) {
      float pre[4];
#pragma unroll
      for (int g = 0; g < 4; ++g) {
        int col = g * 8 + jj;
        pre[g] = gl[(0 * 32 + b) * 33 + col] + gl[(1 * 32 + b) * 33 + col] +
                 gl[(2 * 32 + b) * 33 + col] + gl[(3 * 32 + b) * 33 + col] +
                 bhv[g];
      }
      if (layer == 0) {
        pre[0] += bf2f((ushort_t)(xgu.x & 0xffff));
        pre[1] += bf2f((ushort_t)(xgu.x >> 16));
        pre[2] += bf2f((ushort_t)(xgu.y & 0xffff));
        pre[3] += bf2f((ushort_t)(xgu.y >> 16));
      }
      float ig = sigf(pre[0]), og = sigf(pre[1]);
      float zg = sigf(pre[2]), fg = sigf(pre[3]);
      c_st = c_st * fg + zg - ig;
      float hv_ = sigf(c_st) - og;
      if (layer) out_f[(size_t)t * 32768 + cidx] = hv_;

      ushort_t hb = f2bf(hv_);
      int partner = __shfl_down((int)hb, 1, 64);
      if ((tid & 1) == 0) {
        uint_t packed =
            (uint_t)hb | (((uint_t)(unsigned short)partner) << 16);
        uint_t* dst = hppd +
            ((layer ? ((t & 1) << 14) : ((t & 3) << 14)) + (cidx >> 1));
        asm volatile("global_store_dword %0, %1, off sc0 sc1"
                     :: "v"(dst), "v"(packed) : "memory");
      }
      if (t == T_STEPS - 1) {
        hfinb[layer * 32768 + cidx] = hv_;
        cfinb[layer * 32768 + cidx] = c_st;
      }
    }

    // ---- publish: drain all waves' stores, then set own flag ----
    asm volatile("s_waitcnt vmcnt(0)" ::: "memory");
    __syncthreads();
    if (tid == 0)
      __hip_atomic_store(&fown[wgl], (uint_t)(t + 1), __ATOMIC_RELAXED,
                         __HIP_MEMORY_SCOPE_AGENT);
    if (layer == 0) xgu = xgn;
  }
}

// ---------------------------------------------------------------------------
extern "C" void kernel_launch(void* const* d_in, const int* in_sizes, int n_in,
                              void* d_out, int out_size, void* d_ws,
                              size_t ws_size, hipStream_t stream) {
  (void)in_sizes; (void)n_in; (void)out_size; (void)ws_size;
  const float* x = (const float*)d_in[0];
  const float* h0 = (const float*)d_in[1];
  const float* c0 = (const float*)d_in[2];
  const float* W0 = (const float*)d_in[3];
  const float* R0 = (const float*)d_in[4];
  const float* bi0 = (const float*)d_in[5];
  const float* bh0 = (const float*)d_in[6];
  const float* W1 = (const float*)d_in[7];
  const float* R1 = (const float*)d_in[8];
  const float* bi1 = (const float*)d_in[9];
  const float* bh1 = (const float*)d_in[10];
  float* outp = (float*)d_out;

  // ws: Wbf0 8MB | xg0p 128MB | hpp0 256KB (4 slots) | hpp1 128KB | flags
  char* ws = (char*)d_ws;
  ushort_t* Wbf0 = (ushort_t*)ws;
  ushort_t* xg0p = (ushort_t*)(ws + 8388608);
  ushort_t* hpp0 = (ushort_t*)(ws + 8388608 + 134217728);
  ushort_t* hpp1 = (ushort_t*)((char*)hpp0 + 262144);
  uint_t* flags0 = (uint_t*)((char*)hpp1 + 131072);
  uint_t* flags1 = flags0 + 128;

  const int REC_LDS = 131072 + 4 * 32 * 33 * 4;  // 147968 B
  (void)hipFuncSetAttribute((const void*)fused_rec,
                            hipFuncAttributeMaxDynamicSharedMemorySize,
                            REC_LDS);
  (void)hipMemsetAsync(flags0, 0, 256 * sizeof(uint_t), stream);

  float* hfinb = outp + 16777216;  // [2][32][1024]
  float* cfinb = hfinb + 65536;    // [2][32][1024]

  cvt_f32_bf16<<<dim3(1024), dim3(256), 0, stream>>>(W0, Wbf0, 1048576);
  init_h<<<dim3(64), dim3(256), 0, stream>>>(h0, hpp0, hpp1);
  gemm_xg<<<dim3(128, 32), dim3(256), 0, stream>>>(x, Wbf0, bi0, xg0p);
  fused_rec<<<dim3(NWG), dim3(512), REC_LDS, stream>>>(
      xg0p, R0, R1, W1, bh0, bi1, bh1, c0, outp, hfinb, cfinb,
      hpp0, hpp1, flags0, flags1);
}

// Round 12
// 4319.983 us; speedup vs baseline: 2.0102x; 1.0243x over previous
//
#include <hip/hip_runtime.h>

typedef unsigned short ushort_t;
typedef unsigned int uint_t;
typedef __bf16 bf16x8 __attribute__((ext_vector_type(8)));
typedef float f32x4 __attribute__((ext_vector_type(4)));

#define T_STEPS 512
#define NWG 256

union bfu { uint4 u; bf16x8 v; };

__device__ __forceinline__ float bf2f(ushort_t u) {
  union { unsigned u; float f; } v; v.u = ((unsigned)u) << 16; return v.f;
}
__device__ __forceinline__ ushort_t f2bf(float f) {
  union { float f; unsigned u; } v; v.f = f;
  unsigned r = (v.u + 0x7FFFu + ((v.u >> 16) & 1u)) >> 16;
  return (ushort_t)r;
}
__device__ __forceinline__ uint_t pack2(float a, float b) {
  return (uint_t)f2bf(a) | ((uint_t)f2bf(b) << 16);
}
__device__ __forceinline__ float sigf(float x) {
  return 1.0f / (1.0f + __expf(-x));
}

// ---------------------------------------------------------------------------
__global__ void __launch_bounds__(256) cvt_f32_bf16(
    const float* __restrict__ in, ushort_t* __restrict__ outp, int n4) {
  int i = blockIdx.x * 256 + threadIdx.x;
  const int stride = gridDim.x * 256;
  for (; i < n4; i += stride) {
    float4 v = ((const float4*)in)[i];
    ushort4 o;
    o.x = f2bf(v.x); o.y = f2bf(v.y); o.z = f2bf(v.z); o.w = f2bf(v.w);
    ((ushort4*)outp)[i] = o;
  }
}

// ---------------------------------------------------------------------------
// init: h0_all (fp32 [2][32][1024]) -> hpp0 ring slot 3 / hpp1 slot 1 (bf16)
// ---------------------------------------------------------------------------
__global__ void __launch_bounds__(256) init_h(
    const float* __restrict__ h0_all, ushort_t* __restrict__ hpp0,
    ushort_t* __restrict__ hpp1) {
  int i = blockIdx.x * 256 + threadIdx.x;  // 16384 threads x float4
  int l = i >> 13, j = i & 8191;
  float4 v = ((const float4*)(h0_all + l * 32768))[j];
  ushort4 o;
  o.x = f2bf(v.x); o.y = f2bf(v.y); o.z = f2bf(v.z); o.w = f2bf(v.w);
  ((ushort4*)(l ? (hpp1 + 32768) : (hpp0 + 98304)))[j] = o;
}

// ---------------------------------------------------------------------------
// GEMM: xg0p[m][pc] = sum_k X[m][k]*W0[n][k] + bi0[n], column-permuted
// pc = ((n&1023)>>3)*32 + (n&7)*4 + (n>>10).  X fp32 (reg-staged cvt), W bf16.
// ---------------------------------------------------------------------------
__global__ void __launch_bounds__(256, 1) gemm_xg(
    const float* __restrict__ X, const ushort_t* __restrict__ Wm,
    const float* __restrict__ bi, ushort_t* __restrict__ outp) {
  __shared__ char smem[65536];
  const int tid = threadIdx.x;
  const int lane = tid & 63, w = tid >> 6;
  const int m0 = blockIdx.x * 128, n0 = blockIdx.y * 128;
  const int wr = w >> 1, wc = w & 1;
  const int lr = lane & 15, kg = lane >> 4;
  const int ar_ = tid & 127;
  const int abq = (tid >> 7) * 4;

  f32x4 acc[4][4] = {};
  float4 fa[8];

  auto stageA_issue = [&](int kt) {
    const float* src = X + (size_t)(m0 + ar_) * 1024 + kt * 64 + abq * 8;
#pragma unroll
    for (int i = 0; i < 4; ++i) {
      fa[2 * i] = *(const float4*)(src + i * 8);
      fa[2 * i + 1] = *(const float4*)(src + i * 8 + 4);
    }
  };
  auto stageA_write = [&](int p) {
    char* sA = smem + p * 32768;
#pragma unroll
    for (int i = 0; i < 4; ++i) {
      int blk = abq + i;
      uint4 o;
      o.x = pack2(fa[2 * i].x, fa[2 * i].y);
      o.y = pack2(fa[2 * i].z, fa[2 * i].w);
      o.z = pack2(fa[2 * i + 1].x, fa[2 * i + 1].y);
      o.w = pack2(fa[2 * i + 1].z, fa[2 * i + 1].w);
      *(uint4*)(sA + ar_ * 128 + ((blk ^ (ar_ & 7)) << 4)) = o;
    }
  };
  auto stageB = [&](int kt, int p) {
    const int ks = kt * 64;
    char* sB = smem + p * 32768 + 16384;
#pragma unroll
    for (int i = 0; i < 4; ++i) {
      int wi = w * 4 + i;
      int e = wi * 64 + lane;
      int row = e >> 3, pb = e & 7;
      int kb = pb ^ (row & 7);
      const ushort_t* gB = Wm + (size_t)(n0 + row) * 1024 + ks + kb * 8;
      __builtin_amdgcn_global_load_lds(
          (const __attribute__((address_space(1))) void*)gB,
          (__attribute__((address_space(3))) void*)(sB + wi * 1024), 16, 0, 0);
    }
  };

  stageA_issue(0);
  stageB(0, 0);
  stageA_write(0);
  __syncthreads();
#pragma unroll 1
  for (int kt = 0; kt < 16; ++kt) {
    const int p = kt & 1;
    if (kt < 15) { stageA_issue(kt + 1); stageB(kt + 1, p ^ 1); }
    const char* sA = smem + p * 32768;
    const char* sB = sA + 16384;
#pragma unroll
    for (int k2 = 0; k2 < 2; ++k2) {
      bf16x8 af[4], bf[4];
#pragma unroll
      for (int mt = 0; mt < 4; ++mt) {
        int ar = wr * 64 + mt * 16 + lr;
        int kb = k2 * 4 + kg;
        af[mt] = *(const bf16x8*)(sA + ar * 128 + ((kb ^ (ar & 7)) << 4));
      }
#pragma unroll
      for (int nt = 0; nt < 4; ++nt) {
        int br = wc * 64 + nt * 16 + lr;
        int kb = k2 * 4 + kg;
        bf[nt] = *(const bf16x8*)(sB + br * 128 + ((kb ^ (br & 7)) << 4));
      }
#pragma unroll
      for (int mt = 0; mt < 4; ++mt)
#pragma unroll
        for (int nt = 0; nt < 4; ++nt)
          acc[mt][nt] = __builtin_amdgcn_mfma_f32_16x16x32_bf16(
              af[mt], bf[nt], acc[mt][nt], 0, 0, 0);
    }
    if (kt < 15) stageA_write(p ^ 1);
    __syncthreads();
  }
#pragma unroll
  for (int nt = 0; nt < 4; ++nt) {
    int gc = n0 + wc * 64 + nt * 16 + lr;
    int pc = ((gc & 1023) >> 3) * 32 + (gc & 7) * 4 + (gc >> 10);
    float bv = bi[gc];
#pragma unroll
    for (int mt = 0; mt < 4; ++mt) {
#pragma unroll
      for (int r = 0; r < 4; ++r) {
        int gr = m0 + wr * 64 + mt * 16 + kg * 4 + r;
        outp[(size_t)gr * 4096 + pc] = f2bf(acc[mt][nt][r] + bv);
      }
    }
  }
}

// ---------------------------------------------------------------------------
// Fused 2-layer wavefront recurrence, decoupled barriers + prefetch pipeline.
// 256 WGs x 512 thr. WGs 0..127 = layer 0, 128..255 = layer 1.
// Layer 0: h0 ring (4 slots), runs ahead; xg prefetched post-flag (off-chain).
// Layer 1: prefetches h0(t+1) to regs during step t (cross-wait flags0>=t+2);
// per step: h0->LDS (no wait), issue h1 + prefetch, W1xh0 MFMAs while h1 in
// flight, vmcnt(8), stage h1, R1xh1 MFMAs. gl is [b][q][col] (stride 132).
// gates i,o,z,f:  c = c*f + z - i;  h = sig(c) - o.
// ---------------------------------------------------------------------------
#define GLD4(dst, addr)                                        \
  asm volatile("global_load_dwordx4 %0, %1, off sc0 sc1"      \
               : "=v"(dst) : "v"(addr))
#define WAITN(N)                                               \
  do {                                                         \
    asm volatile("s_waitcnt vmcnt(" #N ")" ::: "memory");      \
    __builtin_amdgcn_sched_barrier(0);                         \
  } while (0)

__global__ void __launch_bounds__(512, 1) fused_rec(
    const ushort_t* __restrict__ xg0p, const float* __restrict__ R0,
    const float* __restrict__ R1, const float* __restrict__ W1,
    const float* __restrict__ bh0, const float* __restrict__ bi1,
    const float* __restrict__ bh1, const float* __restrict__ c0_all,
    float* __restrict__ out_f, float* __restrict__ hfinb,
    float* __restrict__ cfinb, ushort_t* __restrict__ hpp0,
    ushort_t* __restrict__ hpp1, uint_t* __restrict__ flags0,
    uint_t* __restrict__ flags1) {
  extern __shared__ char smem[];
  char* hl = smem;                      // h1 [32][2048B] | h0 at +65536
  float* gl = (float*)(smem + 131072);  // [32][132] f32: b*132 + q*33 + col

  const int tid = threadIdx.x;
  const int wg = blockIdx.x;
  const int layer = wg >> 7;
  const int wgl = wg & 127;
  const int j0 = wgl * 8;
  const int lane = tid & 63, w = tid >> 6;
  const int n16 = (w & 1) << 4;   // gate-col half
  const int kq = w >> 1;          // K quarter
  const int lr16 = lane & 15, kg = lane >> 4;
  const int b = (tid >> 3) & 31, jj = tid & 7;
  const int rx = lr16 & 7;

  uint_t* fown = layer ? flags1 : flags0;
  uint_t* foth = layer ? flags0 : flags1;

  // ---- one-time: weight fragments -> registers ----
  const int c = n16 + lr16;
  const int r_w = ((c >> 3) << 10) + j0 + (c & 7);
  bf16x8 breg[16];
  if (layer == 0) {
#pragma unroll
    for (int i = 0; i < 8; ++i) {
      const float* src = R0 + (size_t)r_w * 1024 + kq * 256 + i * 32 + kg * 8;
      float4 f0 = *(const float4*)src;
      float4 f1 = *(const float4*)(src + 4);
      bfu o;
      o.u.x = pack2(f0.x, f0.y); o.u.y = pack2(f0.z, f0.w);
      o.u.z = pack2(f1.x, f1.y); o.u.w = pack2(f1.z, f1.w);
      breg[i] = o.v;
    }
  } else {
    // breg[0..7] = R1 quarter kq; breg[8..15] = W1 quarter kq
#pragma unroll
    for (int i = 0; i < 8; ++i) {
      const float* src = R1 + (size_t)r_w * 1024 + kq * 256 + i * 32 + kg * 8;
      float4 f0 = *(const float4*)src;
      float4 f1 = *(const float4*)(src + 4);
      bfu o;
      o.u.x = pack2(f0.x, f0.y); o.u.y = pack2(f0.z, f0.w);
      o.u.z = pack2(f1.x, f1.y); o.u.w = pack2(f1.z, f1.w);
      breg[i] = o.v;
    }
#pragma unroll
    for (int i = 0; i < 8; ++i) {
      const float* src = W1 + (size_t)r_w * 1024 + kq * 256 + i * 32 + kg * 8;
      float4 f0 = *(const float4*)src;
      float4 f1 = *(const float4*)(src + 4);
      bfu o;
      o.u.x = pack2(f0.x, f0.y); o.u.y = pack2(f0.z, f0.w);
      o.u.z = pack2(f1.x, f1.y); o.u.w = pack2(f1.z, f1.w);
      breg[8 + i] = o.v;
    }
  }

  float bhv[4];
#pragma unroll
  for (int g = 0; g < 4; ++g) {
    int gi = g * 1024 + j0 + jj;
    bhv[g] = layer ? (bi1[gi] + bh1[gi]) : bh0[gi];
  }
  const int cidx = b * 1024 + j0 + jj;
  float c_st = c0_all[layer * 32768 + cidx];
  uint_t* hppd = (uint_t*)(layer ? hpp1 : hpp0);

  const char* xgbase = (const char*)xg0p +
      ((size_t)b * 4096 + (size_t)wgl * 32 + (size_t)jj * 4) * 2;
  uint2 xgu = {0, 0};
  if (layer == 0 && tid < 256)
    asm volatile("global_load_dwordx2 %0, %1, off" : "=v"(xgu) : "v"(xgbase));
  uint4 hv0p[8];  // layer-1 persistent h0 prefetch regs
  __syncthreads();

#pragma unroll 1
  for (int t = 0; t < T_STEPS; ++t) {
    // ---- wait phase ----
    {
      const int genOwn = t;
      const int genOth =
          layer ? ((t + 2 > T_STEPS) ? T_STEPS : (t + 2)) : (t - 3);
      if (tid < 128) {
        while ((int)__hip_atomic_load(&fown[tid], __ATOMIC_RELAXED,
                                      __HIP_MEMORY_SCOPE_AGENT) < genOwn)
          __builtin_amdgcn_s_sleep(1);
      } else if (tid < 256) {
        while ((int)__hip_atomic_load(&foth[tid - 128], __ATOMIC_RELAXED,
                                      __HIP_MEMORY_SCOPE_AGENT) < genOth)
          __builtin_amdgcn_s_sleep(1);
      }
      __syncthreads();
      asm volatile("" ::: "memory");
    }

    f32x4 acc0 = {0.f, 0.f, 0.f, 0.f}, acc1 = {0.f, 0.f, 0.f, 0.f};
    if (layer == 0) {
      uint4 hv[8];
      const char* hsrc =
          (const char*)hpp0 + (((t + 3) & 3) << 16) + tid * 16;
#pragma unroll
      for (int l = 0; l < 8; ++l) GLD4(hv[l], hsrc + l * 8192);
      WAITN(0);
#pragma unroll
      for (int l = 0; l < 8; ++l) {
        int idx = l * 512 + tid;
        int row = idx >> 7, kb = idx & 127;
        *(uint4*)(hl + row * 2048 + ((kb ^ (row & 7)) << 4)) = hv[l];
      }
      __syncthreads();
      const char* a0 = hl + lr16 * 2048;
      const char* a1 = hl + (16 + lr16) * 2048;
#pragma unroll
      for (int i = 0; i < 8; ++i) {
        int kb = kq * 32 + i * 4 + kg;
        bf16x8 av0 = *(const bf16x8*)(a0 + ((kb ^ rx) << 4));
        bf16x8 av1 = *(const bf16x8*)(a1 + ((kb ^ rx) << 4));
        acc0 = __builtin_amdgcn_mfma_f32_16x16x32_bf16(av0, breg[i], acc0,
                                                       0, 0, 0);
        acc1 = __builtin_amdgcn_mfma_f32_16x16x32_bf16(av1, breg[i], acc1,
                                                       0, 0, 0);
      }
    } else {
      // ---- layer 1: two-phase pipeline ----
      if (t == 0) {
        const char* h0src = (const char*)hpp0 + tid * 16;  // slot 0
#pragma unroll
        for (int l = 0; l < 8; ++l) GLD4(hv0p[l], h0src + l * 8192);
      }
      WAITN(0);  // prefetched h0(t) (or t=0 loads) complete
#pragma unroll
      for (int l = 0; l < 8; ++l) {
        int idx = l * 512 + tid;
        int row = idx >> 7, kb = idx & 127;
        *(uint4*)(hl + 65536 + row * 2048 + ((kb ^ (row & 7)) << 4)) =
            hv0p[l];
      }
      uint4 hv1[8];
      const char* h1src =
          (const char*)hpp1 + (((t + 1) & 1) << 16) + tid * 16;
#pragma unroll
      for (int l = 0; l < 8; ++l) GLD4(hv1[l], h1src + l * 8192);
      // prefetch h0(t+1) (unconditional; garbage at t=511, never consumed)
      const char* h0n =
          (const char*)hpp0 + (((t + 1) & 3) << 16) + tid * 16;
#pragma unroll
      for (int l = 0; l < 8; ++l) GLD4(hv0p[l], h0n + l * 8192);
      __syncthreads();  // h0 LDS ready
      // phase A: W1 x h0(t) while h1 loads in flight
      {
        const char* a0 = hl + 65536 + lr16 * 2048;
        const char* a1 = hl + 65536 + (16 + lr16) * 2048;
#pragma unroll
        for (int i = 0; i < 8; ++i) {
          int kb = kq * 32 + i * 4 + kg;
          bf16x8 av0 = *(const bf16x8*)(a0 + ((kb ^ rx) << 4));
          bf16x8 av1 = *(const bf16x8*)(a1 + ((kb ^ rx) << 4));
          acc0 = __builtin_amdgcn_mfma_f32_16x16x32_bf16(av0, breg[8 + i],
                                                         acc0, 0, 0, 0);
          acc1 = __builtin_amdgcn_mfma_f32_16x16x32_bf16(av1, breg[8 + i],
                                                         acc1, 0, 0, 0);
        }
      }
      WAITN(8);  // h1 arrived (prefetch still outstanding)
#pragma unroll
      for (int l = 0; l < 8; ++l) {
        int idx = l * 512 + tid;
        int row = idx >> 7, kb = idx & 127;
        *(uint4*)(hl + row * 2048 + ((kb ^ (row & 7)) << 4)) = hv1[l];
      }
      __syncthreads();  // h1 LDS ready
      // phase B: R1 x h1(t-1)
      {
        const char* a0 = hl + lr16 * 2048;
        const char* a1 = hl + (16 + lr16) * 2048;
#pragma unroll
        for (int i = 0; i < 8; ++i) {
          int kb = kq * 32 + i * 4 + kg;
          bf16x8 av0 = *(const bf16x8*)(a0 + ((kb ^ rx) << 4));
          bf16x8 av1 = *(const bf16x8*)(a1 + ((kb ^ rx) << 4));
          acc0 = __builtin_amdgcn_mfma_f32_16x16x32_bf16(av0, breg[i], acc0,
                                                         0, 0, 0);
          acc1 = __builtin_amdgcn_mfma_f32_16x16x32_bf16(av1, breg[i], acc1,
                                                         0, 0, 0);
        }
      }
    }
    // gl[b][q][col] partials (conflict-free: 2-way max)
#pragma unroll
    for (int r = 0; r < 4; ++r) {
      gl[(kg * 4 + r) * 132 + kq * 33 + n16 + lr16] = acc0[r];
      gl[(16 + kg * 4 + r) * 132 + kq * 33 + n16 + lr16] = acc1[r];
    }
    __syncthreads();

    if (tid < 256) {
      float pre[4];
#pragma unroll
      for (int g = 0; g < 4; ++g) {
        int col = g * 8 + jj;
        pre[g] = gl[b * 132 + 0 * 33 + col] + gl[b * 132 + 1 * 33 + col] +
                 gl[b * 132 + 2 * 33 + col] + gl[b * 132 + 3 * 33 + col] +
                 bhv[g];
      }
      if (layer == 0) {
        pre[0] += bf2f((ushort_t)(xgu.x & 0xffff));
        pre[1] += bf2f((ushort_t)(xgu.x >> 16));
        pre[2] += bf2f((ushort_t)(xgu.y & 0xffff));
        pre[3] += bf2f((ushort_t)(xgu.y >> 16));
      }
      float ig = sigf(pre[0]), og = sigf(pre[1]);
      float zg = sigf(pre[2]), fg = sigf(pre[3]);
      c_st = c_st * fg + zg - ig;
      float hv_ = sigf(c_st) - og;
      if (layer) out_f[(size_t)t * 32768 + cidx] = hv_;

      ushort_t hb = f2bf(hv_);
      int partner = __shfl_down((int)hb, 1, 64);
      if ((tid & 1) == 0) {
        uint_t packed =
            (uint_t)hb | (((uint_t)(unsigned short)partner) << 16);
        uint_t* dst = hppd +
            ((layer ? ((t & 1) << 14) : ((t & 3) << 14)) + (cidx >> 1));
        asm volatile("global_store_dword %0, %1, off sc0 sc1"
                     :: "v"(dst), "v"(packed) : "memory");
      }
      if (t == T_STEPS - 1) {
        hfinb[layer * 32768 + cidx] = hv_;
        cfinb[layer * 32768 + cidx] = c_st;
      }
    }

    // ---- publish: drain stores, set flag, then (layer 0) prefetch xg ----
    asm volatile("s_waitcnt vmcnt(0)" ::: "memory");
    __syncthreads();
    if (tid == 0)
      __hip_atomic_store(&fown[wgl], (uint_t)(t + 1), __ATOMIC_RELAXED,
                         __HIP_MEMORY_SCOPE_AGENT);
    if (layer == 0 && tid < 256 && t + 1 < T_STEPS)
      asm volatile("global_load_dwordx2 %0, %1, off"
                   : "=v"(xgu) : "v"(xgbase + (size_t)(t + 1) * 262144));
  }
}

// ---------------------------------------------------------------------------
extern "C" void kernel_launch(void* const* d_in, const int* in_sizes, int n_in,
                              void* d_out, int out_size, void* d_ws,
                              size_t ws_size, hipStream_t stream) {
  (void)in_sizes; (void)n_in; (void)out_size; (void)ws_size;
  const float* x = (const float*)d_in[0];
  const float* h0 = (const float*)d_in[1];
  const float* c0 = (const float*)d_in[2];
  const float* W0 = (const float*)d_in[3];
  const float* R0 = (const float*)d_in[4];
  const float* bi0 = (const float*)d_in[5];
  const float* bh0 = (const float*)d_in[6];
  const float* W1 = (const float*)d_in[7];
  const float* R1 = (const float*)d_in[8];
  const float* bi1 = (const float*)d_in[9];
  const float* bh1 = (const float*)d_in[10];
  float* outp = (float*)d_out;

  // ws: Wbf0 8MB | xg0p 128MB | hpp0 256KB (4 slots) | hpp1 128KB | flags
  char* ws = (char*)d_ws;
  ushort_t* Wbf0 = (ushort_t*)ws;
  ushort_t* xg0p = (ushort_t*)(ws + 8388608);
  ushort_t* hpp0 = (ushort_t*)(ws + 8388608 + 134217728);
  ushort_t* hpp1 = (ushort_t*)((char*)hpp0 + 262144);
  uint_t* flags0 = (uint_t*)((char*)hpp1 + 131072);
  uint_t* flags1 = flags0 + 128;

  const int REC_LDS = 131072 + 32 * 132 * 4;  // 147968 B
  (void)hipFuncSetAttribute((const void*)fused_rec,
                            hipFuncAttributeMaxDynamicSharedMemorySize,
                            REC_LDS);
  (void)hipMemsetAsync(flags0, 0, 256 * sizeof(uint_t), stream);

  float* hfinb = outp + 16777216;  // [2][32][1024]
  float* cfinb = hfinb + 65536;    // [2][32][1024]

  cvt_f32_bf16<<<dim3(1024), dim3(256), 0, stream>>>(W0, Wbf0, 1048576);
  init_h<<<dim3(64), dim3(256), 0, stream>>>(h0, hpp0, hpp1);
  gemm_xg<<<dim3(128, 32), dim3(256), 0, stream>>>(x, Wbf0, bi0, xg0p);
  fused_rec<<<dim3(NWG), dim3(512), REC_LDS, stream>>>(
      xg0p, R0, R1, W1, bh0, bi1, bh1, c0, outp, hfinb, cfinb,
      hpp0, hpp1, flags0, flags1);
}